// Round 9
// baseline (1286.108 us; speedup 1.0000x reference)
//
#include <hip/hip_runtime.h>
#include <hip/hip_bf16.h>
#include <math.h>

// Mixtral decoder layer, MI355X. T=2048 H=2048 NH=16 NKV=4 HD=128 I=4096 E=8 TOPK=2.
// Pre-router path (QKV, attn, o_proj): 3-pass bf16-split MFMA (~fp32 accurate) so the
// router top-k matches the fp32 reference; MoE expert path is plain bf16.
// R9: w13 reverted to proven R7 single-buffer; attn stages only Kh/Vh in LDS (80KB ->
// 2 blocks/CU) and reads Kl/Vl direct from L2 (halves LDS BW, the measured bottleneck).

#define T_  2048
#define H_  2048
#define NH  16
#define NKV 4
#define HD  128
#define II_ 4096
#define NE  8
#define EPS 1e-5f
#define PROWS 6144   // padded permuted rows

typedef __bf16 bf16x8 __attribute__((ext_vector_type(8)));
typedef float  f32x4  __attribute__((ext_vector_type(4)));
typedef unsigned short u16;

__device__ __forceinline__ u16 f2b(float f){ __bf16 b = (__bf16)f; return __builtin_bit_cast(u16, b); }
__device__ __forceinline__ float b2f(u16 u){ return (float)__builtin_bit_cast(__bf16, u); }

__device__ __forceinline__ void gll16(const void* g, void* l){
  __builtin_amdgcn_global_load_lds(
      (const __attribute__((address_space(1))) unsigned int*)g,
      (__attribute__((address_space(3))) unsigned int*)l, 16, 0, 0);
}

__device__ __forceinline__ bf16x8 cvt8(f32x4 a, f32x4 b){
  uint4 u;
  u.x = (unsigned)f2b(a[0]) | ((unsigned)f2b(a[1])<<16);
  u.y = (unsigned)f2b(a[2]) | ((unsigned)f2b(a[3])<<16);
  u.z = (unsigned)f2b(b[0]) | ((unsigned)f2b(b[1])<<16);
  u.w = (unsigned)f2b(b[2]) | ((unsigned)f2b(b[3])<<16);
  return __builtin_bit_cast(bf16x8, u);
}

// ---------------- fp32 -> packed bf16 streaming conversion ----------------
__global__ __launch_bounds__(256) void mx_cvt(const float* __restrict__ s,
                                              u16* __restrict__ d, int n8)
{
  int i = blockIdx.x*256 + threadIdx.x;
  int stride = gridDim.x*256;
  for (; i < n8; i += stride){
    const f32x4* p = (const f32x4*)s + 2*(size_t)i;
    f32x4 a = p[0], b = p[1];
    uint4 u;
    u.x = (unsigned)f2b(a[0]) | ((unsigned)f2b(a[1])<<16);
    u.y = (unsigned)f2b(a[2]) | ((unsigned)f2b(a[3])<<16);
    u.z = (unsigned)f2b(b[0]) | ((unsigned)f2b(b[1])<<16);
    u.w = (unsigned)f2b(b[2]) | ((unsigned)f2b(b[3])<<16);
    ((uint4*)d)[i] = u;
  }
}

// ---------------- fp32 -> split (hi, lo) bf16 conversion ----------------
__global__ __launch_bounds__(256) void mx_cvt_split(const float* __restrict__ s,
                                                    u16* __restrict__ hi,
                                                    u16* __restrict__ lo, int n8)
{
  int i = blockIdx.x*256 + threadIdx.x;
  int stride = gridDim.x*256;
  for (; i < n8; i += stride){
    const f32x4* p = (const f32x4*)s + 2*(size_t)i;
    f32x4 a = p[0], b = p[1];
    uint4 uh, ul;
    u16 h0,h1,h2,h3;
    h0=f2b(a[0]); h1=f2b(a[1]); h2=f2b(a[2]); h3=f2b(a[3]);
    uh.x = (unsigned)h0 | ((unsigned)h1<<16);
    uh.y = (unsigned)h2 | ((unsigned)h3<<16);
    ul.x = (unsigned)f2b(a[0]-b2f(h0)) | ((unsigned)f2b(a[1]-b2f(h1))<<16);
    ul.y = (unsigned)f2b(a[2]-b2f(h2)) | ((unsigned)f2b(a[3]-b2f(h3))<<16);
    h0=f2b(b[0]); h1=f2b(b[1]); h2=f2b(b[2]); h3=f2b(b[3]);
    uh.z = (unsigned)h0 | ((unsigned)h1<<16);
    uh.w = (unsigned)h2 | ((unsigned)h3<<16);
    ul.z = (unsigned)f2b(b[0]-b2f(h0)) | ((unsigned)f2b(b[1]-b2f(h1))<<16);
    ul.w = (unsigned)f2b(b[2]-b2f(h2)) | ((unsigned)f2b(b[3]-b2f(h3))<<16);
    ((uint4*)hi)[i] = uh;
    ((uint4*)lo)[i] = ul;
  }
}

// ---------------- RoPE cos/sin table (double-precision inv_freq) ----------------
__global__ void mx_rope_table(const int* __restrict__ pos, float* __restrict__ cosT,
                              float* __restrict__ sinT)
{
  int i = blockIdx.x*256 + threadIdx.x;            // T*64
  int t = i >> 6, d = i & 63;
  float inv = (float)exp(-((double)d/64.0) * 9.210340371976184); // 10000^{-d/64}
  float f = (float)pos[t] * inv;
  cosT[i] = cosf(f); sinT[i] = sinf(f);
}

// ---------------- fused add + RMSNorm (writes several output forms) ----------------
__global__ __launch_bounds__(256) void mx_addnorm(
    const float* __restrict__ a, const float* __restrict__ b,
    const float* __restrict__ gam, float* __restrict__ res_out,
    u16* __restrict__ hi, u16* __restrict__ lo,
    float* __restrict__ hf, u16* __restrict__ hbf, int* __restrict__ mz)
{
  int t = blockIdx.x, tid = threadIdx.x;
  if (mz && t == 0 && tid < 8) mz[tid] = 0;
  const float4* A4 = (const float4*)a + (size_t)t*512;
  const float4* B4 = (const float4*)b + (size_t)t*512;
  float4 va = A4[tid], vb = B4[tid];
  float4 x0; x0.x=va.x+vb.x; x0.y=va.y+vb.y; x0.z=va.z+vb.z; x0.w=va.w+vb.w;
  va = A4[tid+256]; vb = B4[tid+256];
  float4 x1; x1.x=va.x+vb.x; x1.y=va.y+vb.y; x1.z=va.z+vb.z; x1.w=va.w+vb.w;
  float ss = x0.x*x0.x + x0.y*x0.y + x0.z*x0.z + x0.w*x0.w
           + x1.x*x1.x + x1.y*x1.y + x1.z*x1.z + x1.w*x1.w;
  #pragma unroll
  for (int d=32; d; d>>=1) ss += __shfl_down(ss, d);
  __shared__ float red[4];
  if ((tid&63)==0) red[tid>>6] = ss;
  __syncthreads();
  ss = red[0]+red[1]+red[2]+red[3];
  float scale = rsqrtf(ss * (1.f/2048.f) + EPS);
  float4* R4 = (float4*)res_out + (size_t)t*512;
  R4[tid] = x0; R4[tid+256] = x1;
  const float4* G4p = (const float4*)gam;
  float4 g0 = G4p[tid], g1 = G4p[tid+256];
  float4 y0; y0.x=x0.x*scale*g0.x; y0.y=x0.y*scale*g0.y; y0.z=x0.z*scale*g0.z; y0.w=x0.w*scale*g0.w;
  float4 y1; y1.x=x1.x*scale*g1.x; y1.y=x1.y*scale*g1.y; y1.z=x1.z*scale*g1.z; y1.w=x1.w*scale*g1.w;
  if (hf){ float4* H4 = (float4*)hf + (size_t)t*512; H4[tid]=y0; H4[tid+256]=y1; }
  if (hi){
    ushort4 uh, ul;
    uh.x=f2b(y0.x); ul.x=f2b(y0.x-b2f(uh.x));
    uh.y=f2b(y0.y); ul.y=f2b(y0.y-b2f(uh.y));
    uh.z=f2b(y0.z); ul.z=f2b(y0.z-b2f(uh.z));
    uh.w=f2b(y0.w); ul.w=f2b(y0.w-b2f(uh.w));
    ((ushort4*)hi)[(size_t)t*512 + tid] = uh; ((ushort4*)lo)[(size_t)t*512 + tid] = ul;
    uh.x=f2b(y1.x); ul.x=f2b(y1.x-b2f(uh.x));
    uh.y=f2b(y1.y); ul.y=f2b(y1.y-b2f(uh.y));
    uh.z=f2b(y1.z); ul.z=f2b(y1.z-b2f(uh.z));
    uh.w=f2b(y1.w); ul.w=f2b(y1.w-b2f(uh.w));
    ((ushort4*)hi)[(size_t)t*512 + tid+256] = uh; ((ushort4*)lo)[(size_t)t*512 + tid+256] = ul;
  }
  if (hbf){
    ushort4 u0; u0.x=f2b(y0.x); u0.y=f2b(y0.y); u0.z=f2b(y0.z); u0.w=f2b(y0.w);
    ushort4 u1; u1.x=f2b(y1.x); u1.y=f2b(y1.y); u1.z=f2b(y1.z); u1.w=f2b(y1.w);
    ((ushort4*)hbf)[(size_t)t*512 + tid] = u0; ((ushort4*)hbf)[(size_t)t*512 + tid+256] = u1;
  }
}

// ------- 3-pass split GEMM, gll16 m97 skeleton: C = A(hi,lo) x B(hi,lo)^T, fp32 out -------
template<int NX, int NY>
__global__ __launch_bounds__(256,2) void mx_gemm3g(
    const u16* __restrict__ Ah, const u16* __restrict__ Al,
    const u16* __restrict__ Bh, const u16* __restrict__ Bl,
    float* __restrict__ C, int ldc, int K)
{
  __shared__ u16 AhS[128*64], AlS[128*64], BhS[128*64], BlS[128*64];
  int bid = blockIdx.x;
  int xcd = bid & 7, j = bid >> 3;
  int x = j % NX, p = j / NX;
  int y = xcd + 8*p;
  int m0 = x*128, n0 = y*128;
  int tid = threadIdx.x;
  int w = tid>>6, lane = tid&63, wr = w>>1, wc = w&1, g = lane>>4, lr = lane&15;
  f32x4 acc[4][4];
  #pragma unroll
  for (int fm=0;fm<4;fm++)
    #pragma unroll
    for (int fn=0;fn<4;fn++) acc[fm][fn] = (f32x4){0.f,0.f,0.f,0.f};

  for (int k0 = 0; k0 < K; k0 += 64) {
    #pragma unroll
    for (int i=0;i<4;i++){
      int c = i*256 + tid, r = c>>3, ch = c&7;
      int sw = ((ch ^ (r&7))<<3);
      int db = (i*256 + w*64)<<3;
      gll16(Ah + (size_t)(m0+r)*K + k0 + sw, &AhS[db]);
      gll16(Al + (size_t)(m0+r)*K + k0 + sw, &AlS[db]);
      gll16(Bh + (size_t)(n0+r)*K + k0 + sw, &BhS[db]);
      gll16(Bl + (size_t)(n0+r)*K + k0 + sw, &BlS[db]);
    }
    __syncthreads();
    #pragma unroll
    for (int kk=0;kk<2;kk++){
      bf16x8 ah[4], al[4], bh[4], bl[4];
      #pragma unroll
      for (int fm=0;fm<4;fm++){
        int r = wr*64 + fm*16 + lr;
        int ch = ((kk<<2)+g) ^ (r&7);
        ah[fm] = *(const bf16x8*)(&AhS[(r<<6)+(ch<<3)]);
        al[fm] = *(const bf16x8*)(&AlS[(r<<6)+(ch<<3)]);
      }
      #pragma unroll
      for (int fn=0;fn<4;fn++){
        int r = wc*64 + fn*16 + lr;
        int ch = ((kk<<2)+g) ^ (r&7);
        bh[fn] = *(const bf16x8*)(&BhS[(r<<6)+(ch<<3)]);
        bl[fn] = *(const bf16x8*)(&BlS[(r<<6)+(ch<<3)]);
      }
      __builtin_amdgcn_s_setprio(1);
      #pragma unroll
      for (int fm=0;fm<4;fm++)
        #pragma unroll
        for (int fn=0;fn<4;fn++){
          acc[fm][fn] = __builtin_amdgcn_mfma_f32_16x16x32_bf16(ah[fm], bh[fn], acc[fm][fn],0,0,0);
          acc[fm][fn] = __builtin_amdgcn_mfma_f32_16x16x32_bf16(ah[fm], bl[fn], acc[fm][fn],0,0,0);
          acc[fm][fn] = __builtin_amdgcn_mfma_f32_16x16x32_bf16(al[fm], bh[fn], acc[fm][fn],0,0,0);
        }
      __builtin_amdgcn_s_setprio(0);
    }
    __syncthreads();
  }
  #pragma unroll
  for (int fm=0;fm<4;fm++)
    #pragma unroll
    for (int fn=0;fn<4;fn++)
      #pragma unroll
      for (int i=0;i<4;i++){
        size_t rg = (size_t)(m0 + wr*64 + fm*16 + g*4 + i);
        int cg = n0 + wc*64 + fn*16 + lr;
        C[rg*ldc + cg] = acc[fm][fn][i];
      }
}

// ------------- 3-pass split-bf16 GEMM (fallback, fp32 B in-loop) -------------
template<int NX, int NY>
__global__ __launch_bounds__(256) void mx_gemm3(
    const u16* __restrict__ Ah, const u16* __restrict__ Al, int lda,
    const float* __restrict__ B,
    float* __restrict__ C, int ldc, int K)
{
  const int LDT = 72;
  __shared__ u16 Ash[128*LDT], Asl[128*LDT], Bsh[128*LDT], Bsl[128*LDT];
  int bid = blockIdx.x, x, y;
  if constexpr ((NY & 7) == 0) {
    int xcd = bid & 7, j = bid >> 3;
    x = j % NX; int p = j / NX;
    y = xcd + 8*p;
  } else { x = bid % NX; y = bid / NX; }
  int m0 = x*128, n0 = y*128;
  int tid = threadIdx.x;
  int w = tid>>6, lane = tid&63, wr = w>>1, wc = w&1, g = lane>>4, lr = lane&15;
  f32x4 acc[4][4];
  #pragma unroll
  for (int fm=0;fm<4;fm++)
    #pragma unroll
    for (int fn=0;fn<4;fn++) acc[fm][fn] = (f32x4){0.f,0.f,0.f,0.f};
  for (int k0 = 0; k0 < K; k0 += 64) {
    #pragma unroll
    for (int i=0;i<4;i++){
      int c = i*256 + tid, r = c>>3, ch = c&7;
      *(uint4*)(&Ash[r*LDT + ch*8]) = *(const uint4*)(Ah + (size_t)(m0+r)*lda + k0 + ch*8);
      *(uint4*)(&Asl[r*LDT + ch*8]) = *(const uint4*)(Al + (size_t)(m0+r)*lda + k0 + ch*8);
    }
    #pragma unroll
    for (int i=0;i<8;i++){
      int f = i*256 + tid, r = f>>4, c4 = f&15;
      float4 v = *(const float4*)(B + (size_t)(n0+r)*K + k0 + c4*4);
      ushort4 hv, lv;
      hv.x=f2b(v.x); lv.x=f2b(v.x-b2f(hv.x));
      hv.y=f2b(v.y); lv.y=f2b(v.y-b2f(hv.y));
      hv.z=f2b(v.z); lv.z=f2b(v.z-b2f(hv.z));
      hv.w=f2b(v.w); lv.w=f2b(v.w-b2f(hv.w));
      *(ushort4*)(&Bsh[r*LDT + c4*4]) = hv;
      *(ushort4*)(&Bsl[r*LDT + c4*4]) = lv;
    }
    __syncthreads();
    #pragma unroll
    for (int kk=0;kk<2;kk++){
      bf16x8 ah[4], al[4], bh[4], bl[4];
      #pragma unroll
      for (int fm=0;fm<4;fm++){
        int r = wr*64 + fm*16 + lr;
        ah[fm] = *(const bf16x8*)(&Ash[r*LDT + kk*32 + g*8]);
        al[fm] = *(const bf16x8*)(&Asl[r*LDT + kk*32 + g*8]);
      }
      #pragma unroll
      for (int fn=0;fn<4;fn++){
        int r = wc*64 + fn*16 + lr;
        bh[fn] = *(const bf16x8*)(&Bsh[r*LDT + kk*32 + g*8]);
        bl[fn] = *(const bf16x8*)(&Bsl[r*LDT + kk*32 + g*8]);
      }
      __builtin_amdgcn_s_setprio(1);
      #pragma unroll
      for (int fm=0;fm<4;fm++)
        #pragma unroll
        for (int fn=0;fn<4;fn++){
          acc[fm][fn] = __builtin_amdgcn_mfma_f32_16x16x32_bf16(ah[fm], bh[fn], acc[fm][fn],0,0,0);
          acc[fm][fn] = __builtin_amdgcn_mfma_f32_16x16x32_bf16(ah[fm], bl[fn], acc[fm][fn],0,0,0);
          acc[fm][fn] = __builtin_amdgcn_mfma_f32_16x16x32_bf16(al[fm], bh[fn], acc[fm][fn],0,0,0);
        }
      __builtin_amdgcn_s_setprio(0);
    }
    __syncthreads();
  }
  #pragma unroll
  for (int fm=0;fm<4;fm++)
    #pragma unroll
    for (int fn=0;fn<4;fn++)
      #pragma unroll
      for (int i=0;i<4;i++){
        size_t rg = (size_t)(m0 + wr*64 + fm*16 + g*4 + i);
        int cg = n0 + wc*64 + fn*16 + lr;
        C[rg*ldc + cg] = acc[fm][fn][i];
      }
}

// ------------- MoE w1+w3 fused GEMM + silu epilogue (all-bf16, m97-style, R7) -------------
template<int NY>
__global__ __launch_bounds__(256,2) void mx_moe_w13(
    const u16* __restrict__ A,
    const u16* __restrict__ B1, const u16* __restrict__ B3,
    u16* __restrict__ Y,
    const int* __restrict__ row_map, const int* __restrict__ meta)
{
  __shared__ u16 As[128*64], B1s[128*64], B3s[128*64];
  int bid = blockIdx.x;
  int xcd = bid & 7, j = bid >> 3;
  int x = j & 15, p = j >> 4;
  int panel = xcd + 8*p;                 // < NE*NY
  int e = panel / NY, y = panel % NY;
  if (x >= meta[16+e]) return;
  int rowbase = meta[8+e] + (x<<7);
  const u16* B1p = B1 + ((size_t)e*II_ + y*128)*H_;
  const u16* B3p = B3 + ((size_t)e*II_ + y*128)*H_;
  int tid = threadIdx.x;
  int w = tid>>6, lane = tid&63, wr = w>>1, wc = w&1, g = lane>>4, lr = lane&15;

  f32x4 acc1[4][4], acc3[4][4];
  #pragma unroll
  for (int fm=0;fm<4;fm++)
    #pragma unroll
    for (int fn=0;fn<4;fn++){ acc1[fm][fn]=(f32x4){0,0,0,0}; acc3[fm][fn]=(f32x4){0,0,0,0}; }

  for (int k0 = 0; k0 < H_; k0 += 64) {
    #pragma unroll
    for (int i=0;i<4;i++){
      int c = i*256 + tid, r = c>>3, ch = c&7;
      int sw = (ch ^ (r&7))<<3;
      int db = (i*256 + w*64)<<3;
      int grow = row_map[rowbase + r];
      gll16(A   + (size_t)grow*H_ + k0 + sw, &As[db]);
      gll16(B1p + (size_t)r*H_    + k0 + sw, &B1s[db]);
      gll16(B3p + (size_t)r*H_    + k0 + sw, &B3s[db]);
    }
    __syncthreads();
    #pragma unroll
    for (int kk=0;kk<2;kk++){
      bf16x8 af[4], b1f[4], b3f[4];
      #pragma unroll
      for (int fm=0;fm<4;fm++){
        int r = wr*64 + fm*16 + lr;
        int ch = ((kk<<2)+g) ^ (r&7);
        af[fm] = *(const bf16x8*)(&As[(r<<6)+(ch<<3)]);
      }
      #pragma unroll
      for (int fn=0;fn<4;fn++){
        int r = wc*64 + fn*16 + lr;
        int ch = ((kk<<2)+g) ^ (r&7);
        b1f[fn] = *(const bf16x8*)(&B1s[(r<<6)+(ch<<3)]);
        b3f[fn] = *(const bf16x8*)(&B3s[(r<<6)+(ch<<3)]);
      }
      __builtin_amdgcn_s_setprio(1);
      #pragma unroll
      for (int fm=0;fm<4;fm++)
        #pragma unroll
        for (int fn=0;fn<4;fn++){
          acc1[fm][fn] = __builtin_amdgcn_mfma_f32_16x16x32_bf16(af[fm], b1f[fn], acc1[fm][fn],0,0,0);
          acc3[fm][fn] = __builtin_amdgcn_mfma_f32_16x16x32_bf16(af[fm], b3f[fn], acc3[fm][fn],0,0,0);
        }
      __builtin_amdgcn_s_setprio(0);
    }
    __syncthreads();
  }
  int n0 = y*128 + wc*64;
  #pragma unroll
  for (int fm=0;fm<4;fm++)
    #pragma unroll
    for (int fn=0;fn<4;fn++)
      #pragma unroll
      for (int i=0;i<4;i++){
        size_t rg = (size_t)(rowbase + wr*64 + fm*16 + g*4 + i);
        int cg = n0 + fn*16 + lr;
        float gg = acc1[fm][fn][i], uu = acc3[fm][fn][i];
        float sg = gg / (1.f + __expf(-gg));
        Y[rg*II_ + cg] = f2b(sg * uu);
      }
}

// ------------- MoE w2 GEMM (all-bf16, m97-style): Y2 = Y . w2^T -------------
template<int NY>
__global__ __launch_bounds__(256,2) void mx_moe_w2k(
    const u16* __restrict__ A,       // Y bf16 [PROWS][II_]
    const u16* __restrict__ B,       // w2b bf16 [E][H_][II_]
    float* __restrict__ C,           // Y2 fp32 [PROWS][H_]
    const int* __restrict__ meta)
{
  __shared__ u16 As[128*64], Bs[128*64];
  int bid = blockIdx.x;
  int xcd = bid & 7, j = bid >> 3;
  int x = j & 15, p = j >> 4;
  int panel = xcd + 8*p;                 // < NE*NY
  int e = panel / NY, y = panel % NY;
  if (x >= meta[16+e]) return;
  int rowbase = meta[8+e] + (x<<7);
  const u16* Bp = B + ((size_t)e*H_ + y*128)*II_;
  int tid = threadIdx.x;
  int w = tid>>6, lane = tid&63, wr = w>>1, wc = w&1, g = lane>>4, lr = lane&15;

  f32x4 acc[4][4];
  #pragma unroll
  for (int fm=0;fm<4;fm++)
    #pragma unroll
    for (int fn=0;fn<4;fn++) acc[fm][fn] = (f32x4){0,0,0,0};

  for (int k0 = 0; k0 < II_; k0 += 64) {
    #pragma unroll
    for (int i=0;i<4;i++){
      int c = i*256 + tid, r = c>>3, ch = c&7;
      int sw = (ch ^ (r&7))<<3;
      int db = (i*256 + w*64)<<3;
      gll16(A  + (size_t)(rowbase + r)*II_ + k0 + sw, &As[db]);
      gll16(Bp + (size_t)r*II_             + k0 + sw, &Bs[db]);
    }
    __syncthreads();
    #pragma unroll
    for (int kk=0;kk<2;kk++){
      bf16x8 af[4], bf[4];
      #pragma unroll
      for (int fm=0;fm<4;fm++){
        int r = wr*64 + fm*16 + lr;
        int ch = ((kk<<2)+g) ^ (r&7);
        af[fm] = *(const bf16x8*)(&As[(r<<6)+(ch<<3)]);
      }
      #pragma unroll
      for (int fn=0;fn<4;fn++){
        int r = wc*64 + fn*16 + lr;
        int ch = ((kk<<2)+g) ^ (r&7);
        bf[fn] = *(const bf16x8*)(&Bs[(r<<6)+(ch<<3)]);
      }
      __builtin_amdgcn_s_setprio(1);
      #pragma unroll
      for (int fm=0;fm<4;fm++)
        #pragma unroll
        for (int fn=0;fn<4;fn++)
          acc[fm][fn] = __builtin_amdgcn_mfma_f32_16x16x32_bf16(af[fm], bf[fn], acc[fm][fn],0,0,0);
      __builtin_amdgcn_s_setprio(0);
    }
    __syncthreads();
  }
  int n0 = y*128 + wc*64;
  #pragma unroll
  for (int fm=0;fm<4;fm++)
    #pragma unroll
    for (int fn=0;fn<4;fn++)
      #pragma unroll
      for (int i=0;i<4;i++){
        size_t rg = (size_t)(rowbase + wr*64 + fm*16 + g*4 + i);
        int cg = n0 + fn*16 + lr;
        C[rg*H_ + cg] = acc[fm][fn][i];
      }
}

// ------------- MoE GEMM fallback (R5): BM=256 BN=128 BK=32, fp32 B direct -------------
template<int GATHER, int CBF16, int NYT, int SPLITY>
__global__ __launch_bounds__(512,4) void mx_moe10(
    const u16* __restrict__ A, int lda,
    const float* __restrict__ B1, const float* __restrict__ B2, long long strideB,
    void* __restrict__ C1v, void* __restrict__ C2v, int ldc, int K,
    const int* __restrict__ row_map, const int* __restrict__ meta)
{
  __shared__ u16 AS[3][256*32];
  int bid = blockIdx.x;
  int xcd = bid & 7, j = bid >> 3;
  int x = j & 7, q = j >> 3;
  int panel = xcd + 8*q;
  int e = panel / NYT, y = panel % NYT;
  if (x >= meta[16+e]) return;
  int rowbase = meta[8+e] + x*256;
  int yy = (y < SPLITY) ? y : y - SPLITY;
  const float* Bp = ((y < SPLITY) ? B1 : B2) + (long long)e*strideB + (size_t)(yy*128)*K;
  void* Cv = (y < SPLITY) ? C1v : C2v;
  int tid = threadIdx.x;
  int w = tid>>6, lane = tid&63, wr = w>>2, wc = w&3, g = lane>>4, lr = lane&15;
  const u16 *srcA0, *srcA1;
  {
    int c0 = tid,     r0 = c0>>2;
    int c1 = 512+tid, r1 = c1>>2;
    int s0 = (c0&3) ^ ((r0>>1)&3);
    int s1 = (c1&3) ^ ((r1>>1)&3);
    int w0 = GATHER ? row_map[rowbase+r0] : (rowbase+r0);
    int w1r = GATHER ? row_map[rowbase+r1] : (rowbase+r1);
    srcA0 = A + (size_t)w0*lda + s0*8;
    srcA1 = A + (size_t)w1r*lda + s1*8;
  }
  const float *srcB0, *srcB1;
  {
    int r0 = wc*32 + lr;
    int r1 = wc*32 + 16 + lr;
    srcB0 = Bp + (size_t)r0*K + g*8;
    srcB1 = Bp + (size_t)r1*K + g*8;
  }
  f32x4 acc[8][2];
  #pragma unroll
  for (int fm=0;fm<8;fm++){ acc[fm][0]=(f32x4){0,0,0,0}; acc[fm][1]=(f32x4){0,0,0,0}; }
  f32x4 e0,e1,e2,e3, o0,o1,o2,o3;
  u16 *pa0=&AS[0][0], *pa1=&AS[1][0], *pa2=&AS[2][0];
  int nt = K >> 5;
  auto stageA = [&](u16* as, int k0){
    gll16(srcA0 + k0, as + (w*64)*8);
    gll16(srcA1 + k0, as + (512 + w*64)*8);
  };
  auto issueB = [&](int k0, f32x4& b0, f32x4& b1, f32x4& b2, f32x4& b3){
    b0 = *(const f32x4*)(srcB0 + k0);
    b1 = *(const f32x4*)(srcB0 + k0 + 4);
    b2 = *(const f32x4*)(srcB1 + k0);
    b3 = *(const f32x4*)(srcB1 + k0 + 4);
  };
  auto compute = [&](const u16* as, f32x4 b0, f32x4 b1, f32x4 b2, f32x4 b3){
    bf16x8 bf0 = cvt8(b0,b1), bf1 = cvt8(b2,b3);
    __builtin_amdgcn_s_setprio(1);
    #pragma unroll
    for (int fm=0;fm<8;fm++){
      int r = wr*128 + fm*16 + lr;
      int ch = g ^ ((r>>1)&3);
      bf16x8 af = *(const bf16x8*)(as + r*32 + ch*8);
      acc[fm][0] = __builtin_amdgcn_mfma_f32_16x16x32_bf16(af, bf0, acc[fm][0],0,0,0);
      acc[fm][1] = __builtin_amdgcn_mfma_f32_16x16x32_bf16(af, bf1, acc[fm][1],0,0,0);
    }
    __builtin_amdgcn_s_setprio(0);
  };
  auto rot = [&](){ u16* t0=pa0; pa0=pa1; pa1=pa2; pa2=t0; };
  auto kclamp = [&](int t){ return (t < nt ? t : 0) << 5; };
  issueB(0, e0,e1,e2,e3);
  asm volatile("" ::: "memory");
  stageA(pa0, 0);
  asm volatile("" ::: "memory");
  stageA(pa1, kclamp(1));
  for (int t=0; t<nt; t+=2){
    asm volatile("s_waitcnt vmcnt(2)" ::: "memory");
    __builtin_amdgcn_s_barrier();
    issueB(kclamp(t+1), o0,o1,o2,o3);
    asm volatile("" ::: "memory");
    stageA(pa2, kclamp(t+2));
    compute(pa0, e0,e1,e2,e3);
    rot();
    asm volatile("s_waitcnt vmcnt(2)" ::: "memory");
    __builtin_amdgcn_s_barrier();
    issueB(kclamp(t+2), e0,e1,e2,e3);
    asm volatile("" ::: "memory");
    stageA(pa2, kclamp(t+3));
    compute(pa0, o0,o1,o2,o3);
    rot();
  }
  int n0 = yy*128 + wc*32;
  #pragma unroll
  for (int fm=0;fm<8;fm++)
    #pragma unroll
    for (int fn=0;fn<2;fn++)
      #pragma unroll
      for (int i=0;i<4;i++){
        size_t rg = (size_t)(rowbase + wr*128 + fm*16 + g*4 + i);
        int cg = n0 + fn*16 + lr;
        if (CBF16) ((u16*)Cv)[rg*ldc + cg] = f2b(acc[fm][fn][i]);
        else       ((float*)Cv)[rg*ldc + cg] = acc[fm][fn][i];
      }
}

// ---------------- RoPE apply: qkv fp32 -> split-bf16 Q [h][t][d], K [kv][t][d] ----------------
__global__ __launch_bounds__(256) void mx_rope_apply(const float* __restrict__ qkv,
    const float* __restrict__ cosT, const float* __restrict__ sinT,
    u16* __restrict__ qh, u16* __restrict__ ql, u16* __restrict__ kh, u16* __restrict__ kl)
{
  int t = blockIdx.x*4 + (threadIdx.x>>6);
  int hh = blockIdx.y, d = threadIdx.x & 63;
  const float* row = qkv + (size_t)t*3072;
  float c = cosT[t*64+d], s = sinT[t*64+d];
  float x1, x2; size_t base; u16 *oh, *ol;
  if (hh < NH){ x1 = row[hh*HD+d]; x2 = row[hh*HD+d+64];
     base = ((size_t)hh*T_ + t)*HD; oh = qh; ol = ql; }
  else { int kvh = hh-NH; x1 = row[2048 + kvh*HD + d]; x2 = row[2048 + kvh*HD + d + 64];
     base = ((size_t)kvh*T_ + t)*HD; oh = kh; ol = kl; }
  float o1 = x1*c - x2*s, o2 = x2*c + x1*s;
  u16 a = f2b(o1); oh[base+d]    = a; ol[base+d]    = f2b(o1 - b2f(a));
  u16 b = f2b(o2); oh[base+d+64] = b; ol[base+d+64] = f2b(o2 - b2f(b));
}

// ---------------- V transpose: qkv fp32 -> split-bf16 V^T [kv][d][t] ----------------
__global__ void mx_transpose_v(const float* __restrict__ qkv,
                               u16* __restrict__ vh, u16* __restrict__ vl)
{
  __shared__ float tile[64][132];
  int kv = blockIdx.x, t0 = blockIdx.y*64, tid = threadIdx.x;
  #pragma unroll
  for (int it=0; it<32; ++it){
    int idx = it*256 + tid; int r = idx>>7, d = idx&127;
    tile[r][d] = qkv[(size_t)(t0+r)*3072 + 2560 + kv*HD + d];
  }
  __syncthreads();
  #pragma unroll
  for (int it=0; it<32; ++it){
    int idx = it*256 + tid; int d = idx>>6, j = idx&63;
    float x = tile[j][d];
    u16 a = f2b(x);
    size_t o = ((size_t)kv*HD + d)*T_ + t0 + j;
    vh[o] = a; vl[o] = f2b(x - b2f(a));
  }
}

// ---------------- flash attention, causal GQA, 3-pass split-bf16 ----------------
// Kh/Vh staged in dbuf LDS (64KB); Kl/Vl read direct from global (L2-resident).
// 80KB LDS total -> 2 blocks/CU; LDS read traffic per kt halved.
__global__ __launch_bounds__(256) void mx_attn(
  const u16* __restrict__ qh_, const u16* __restrict__ ql_,
  const u16* __restrict__ kh_, const u16* __restrict__ kl_,
  const u16* __restrict__ vh_, const u16* __restrict__ vl_,
  u16* __restrict__ oh_, u16* __restrict__ ol_)
{
  int h = blockIdx.y, kvh = h >> 2;
  int qt = (h & 8) ? (31 - (int)blockIdx.x) : (int)blockIdx.x;
  int tid = threadIdx.x, w = tid>>6, lane = tid&63, g = lane>>4, lr = lane&15;
  int q0 = qt*64 + w*16;
  __shared__ u16 KV[2][2][8192];          // [buf][Kh, Vh] = 64 KB
  __shared__ u16 Ph[4][1024], Pl[4][1024];

  bf16x8 qfh[4], qfl[4];
  const u16* qrh = qh_ + ((size_t)h*T_ + q0 + lr)*HD;
  const u16* qrl = ql_ + ((size_t)h*T_ + q0 + lr)*HD;
  #pragma unroll
  for (int kk=0;kk<4;kk++){
    qfh[kk] = *(const bf16x8*)(qrh + kk*32 + g*8);
    qfl[kk] = *(const bf16x8*)(qrl + kk*32 + g*8);
  }
  f32x4 o[8];
  #pragma unroll
  for (int nf=0;nf<8;nf++) o[nf] = (f32x4){0.f,0.f,0.f,0.f};
  float mreg[4] = {-3e38f,-3e38f,-3e38f,-3e38f}, lsum[4] = {0.f,0.f,0.f,0.f};

  const u16* kbase = kh_ + (size_t)kvh*T_*HD;
  const u16* lbase = kl_ + (size_t)kvh*T_*HD;   // K lo, direct reads
  const u16* vbase = vh_ + (size_t)kvh*HD*T_;
  const u16* wbase = vl_ + (size_t)kvh*HD*T_;   // V lo, direct reads

  auto stage = [&](int buf, int kvb){
    #pragma unroll
    for (int i=0;i<4;i++){
      int cb = i*256 + w*64;
      int c  = cb + lane;
      int kr = c>>4, kc = ((c&15) ^ (kr&7))<<3;
      gll16(kbase + (size_t)(kvb+kr)*HD + kc, &KV[buf][0][cb*8]);
      int vr = c>>3, vc = ((c&7) ^ (vr&7))<<3;
      gll16(vbase + (size_t)vr*T_ + kvb + vc, &KV[buf][1][cb*8]);
    }
  };

  stage(0, 0);

  for (int kt = 0; kt <= qt; ++kt) {
    int cur = kt & 1;
    int kvb = kt*64;
    if (kt < qt) {
      stage(cur^1, kvb+64);
      asm volatile("s_waitcnt vmcnt(8)" ::: "memory");   // cur tile complete, next in flight
    } else {
      asm volatile("s_waitcnt vmcnt(0)" ::: "memory");
    }
    __builtin_amdgcn_s_barrier();

    // ---- QK^T (3-pass split): Kh from LDS, Kl direct from L2 ----
    f32x4 s[4];
    #pragma unroll
    for (int nf=0;nf<4;nf++) s[nf] = (f32x4){0.f,0.f,0.f,0.f};
    __builtin_amdgcn_s_setprio(1);
    #pragma unroll
    for (int nf=0; nf<4; nf++){
      int row = nf*16 + lr;
      const u16* krl = lbase + (size_t)(kvb + row)*HD;
      #pragma unroll
      for (int kk=0;kk<4;kk++){
        int off = row*128 + ((((kk<<2)+g) ^ (lr&7))<<3);
        bf16x8 kf = *(const bf16x8*)(&KV[cur][0][off]);
        bf16x8 kg = *(const bf16x8*)(krl + kk*32 + g*8);
        s[nf] = __builtin_amdgcn_mfma_f32_16x16x32_bf16(qfh[kk], kf, s[nf],0,0,0);
        s[nf] = __builtin_amdgcn_mfma_f32_16x16x32_bf16(qfh[kk], kg, s[nf],0,0,0);
        s[nf] = __builtin_amdgcn_mfma_f32_16x16x32_bf16(qfl[kk], kf, s[nf],0,0,0);
      }
    }
    __builtin_amdgcn_s_setprio(0);

    // ---- online softmax ----
    float sv[4][4], pm[4];
    #pragma unroll
    for (int i=0;i<4;i++) pm[i] = -3e38f;
    bool diag = (kt == qt);
    #pragma unroll
    for (int nf=0;nf<4;nf++)
      #pragma unroll
      for (int i=0;i<4;i++){
        float v = s[nf][i] * 0.08838834764831845f;
        if (diag && (kvb + nf*16 + lr > q0 + g*4 + i)) v = -1e30f;
        sv[nf][i] = v;
        pm[i] = fmaxf(pm[i], v);
      }
    #pragma unroll
    for (int i=0;i<4;i++)
      #pragma unroll
      for (int d=1; d<16; d<<=1) pm[i] = fmaxf(pm[i], __shfl_xor(pm[i], d));
    float sf[4], psum[4];
    #pragma unroll
    for (int i=0;i<4;i++){
      float nm = fmaxf(mreg[i], pm[i]);
      sf[i] = __expf(mreg[i] - nm);
      mreg[i] = nm; psum[i] = 0.f;
    }
    #pragma unroll
    for (int nf=0;nf<4;nf++)
      #pragma unroll
      for (int i=0;i<4;i++){
        float e = __expf(sv[nf][i] - mreg[i]);
        sv[nf][i] = e; psum[i] += e;
      }
    #pragma unroll
    for (int i=0;i<4;i++){
      #pragma unroll
      for (int d=1; d<16; d<<=1) psum[i] += __shfl_xor(psum[i], d);
      lsum[i] = lsum[i]*sf[i] + psum[i];
    }
    #pragma unroll
    for (int nf=0;nf<8;nf++)
      #pragma unroll
      for (int i=0;i<4;i++) o[nf][i] *= sf[i];

    // ---- P round-trip (per-wave LDS, no barrier needed) ----
    #pragma unroll
    for (int nf=0;nf<4;nf++)
      #pragma unroll
      for (int i=0;i<4;i++){
        int qi = g*4 + i, kv = nf*16 + lr;
        int idx = qi*64 + (kv ^ ((qi&7)<<3));
        u16 hb = f2b(sv[nf][i]);
        Ph[w][idx] = hb;
        Pl[w][idx] = f2b(sv[nf][i] - b2f(hb));
      }

    // ---- PV (3-pass split): Vh from LDS, Vl direct from L2 ----
    #pragma unroll
    for (int kk2=0; kk2<2; kk2++){
      int pidx = lr*64 + ((kk2*32 + g*8) ^ ((lr&7)<<3));
      bf16x8 ph = *(const bf16x8*)(&Ph[w][pidx]);
      bf16x8 pl = *(const bf16x8*)(&Pl[w][pidx]);
      __builtin_amdgcn_s_setprio(1);
      #pragma unroll
      for (int nf=0; nf<8; nf++){
        int row = nf*16 + lr;
        int off = row*64 + ((((kk2<<2)+g) ^ (lr&7))<<3);
        bf16x8 vf = *(const bf16x8*)(&KV[cur][1][off]);
        bf16x8 vg = *(const bf16x8*)(wbase + (size_t)row*T_ + kvb + kk2*32 + g*8);
        o[nf] = __builtin_amdgcn_mfma_f32_16x16x32_bf16(ph, vf, o[nf],0,0,0);
        o[nf] = __builtin_amdgcn_mfma_f32_16x16x32_bf16(ph, vg, o[nf],0,0,0);
        o[nf] = __builtin_amdgcn_mfma_f32_16x16x32_bf16(pl, vf, o[nf],0,0,0);
      }
      __builtin_amdgcn_s_setprio(0);
    }
    __builtin_amdgcn_s_barrier();   // all waves done with buf[cur] before overwrite
  }

  float inv[4];
  #pragma unroll
  for (int i=0;i<4;i++) inv[i] = 1.0f / lsum[i];
  #pragma unroll
  for (int nf=0;nf<8;nf++)
    #pragma unroll
    for (int i=0;i<4;i++){
      float v = o[nf][i] * inv[i];
      size_t oidx = (size_t)(q0 + g*4 + i)*2048 + h*HD + nf*16 + lr;
      u16 hb = f2b(v);
      oh_[oidx] = hb; ol_[oidx] = f2b(v - b2f(hb));
    }
}

// ---------------- router: fp32 logits, top-2, renorm ----------------
__global__ __launch_bounds__(256) void mx_router(
    const float* __restrict__ h2, const float* __restrict__ gw,
    int* __restrict__ meta, int* __restrict__ tki, float* __restrict__ tkw)
{
  int t = blockIdx.x, tid = threadIdx.x;
  float p[8] = {0,0,0,0,0,0,0,0};
  const float* row = h2 + (size_t)t*H_;
  for (int i = tid; i < H_; i += 256) {
    float x = row[i];
    #pragma unroll
    for (int e=0;e<8;e++) p[e] += x * gw[e*H_ + i];
  }
  #pragma unroll
  for (int e=0;e<8;e++)
    #pragma unroll
    for (int d=32; d; d>>=1) p[e] += __shfl_down(p[e], d);
  __shared__ float red[4][8];
  int w = tid>>6;
  if ((tid&63)==0){
    #pragma unroll
    for (int e=0;e<8;e++) red[w][e] = p[e];
  }
  __syncthreads();
  if (tid==0){
    float lg[8];
    #pragma unroll
    for (int e=0;e<8;e++) lg[e] = red[0][e]+red[1][e]+red[2][e]+red[3][e];
    int e0 = 0;
    for (int e=1;e<8;e++) if (lg[e] > lg[e0]) e0 = e;
    int e1 = (e0==0)?1:0;
    for (int e=0;e<8;e++) if (e!=e0 && lg[e] > lg[e1]) e1 = e;
    float w0 = 1.f/(1.f + __expf(lg[e1]-lg[e0]));
    tki[t*2]=e0; tki[t*2+1]=e1; tkw[t*2]=w0; tkw[t*2+1]=1.f-w0;
    atomicAdd(&meta[e0],1); atomicAdd(&meta[e1],1);
  }
}

// meta: [0..7]=counts [8..15]=poff [16..23]=ptiles [24..31]=cursor; gsh = tile granularity shift
__global__ void mx_scan(int* __restrict__ meta, int* __restrict__ perm, int gsh)
{
  if (threadIdx.x == 0){
    int run = 0;
    for (int e=0;e<8;e++){
      meta[8+e] = run;
      int pt = (meta[e] + (1<<gsh) - 1) >> gsh;
      meta[16+e] = pt;
      run += pt << gsh;
      meta[24+e] = 0;
    }
  }
  for (int i = threadIdx.x; i < PROWS; i += 256) perm[i] = 0;
}

__global__ void mx_scatter(const int* __restrict__ tki, int* __restrict__ meta,
                           int* __restrict__ perm, int* __restrict__ slot)
{
  int t = blockIdx.x*256 + threadIdx.x;
  if (t >= T_) return;
  #pragma unroll
  for (int j=0;j<2;j++){
    int e = tki[t*2+j];
    int s = atomicAdd(&meta[24+e], 1);
    int pos = meta[8+e] + s;
    perm[pos] = t;
    slot[t*2+j] = pos;
  }
}

__global__ void mx_silu(u16* __restrict__ y1, const u16* __restrict__ y3)
{
  size_t base = ((size_t)blockIdx.x*256 + threadIdx.x)*8;
  uint4 a = *(uint4*)(y1+base);
  uint4 b = *(const uint4*)(y3+base);
  u16* ap = (u16*)&a; u16* bp = (u16*)&b;
  uint4 r; u16* rp = (u16*)&r;
  #pragma unroll
  for (int j=0;j<8;j++){
    float gg = b2f(ap[j]), uu = b2f(bp[j]);
    float sg = gg / (1.f + __expf(-gg));
    rp[j] = f2b(sg * uu);
  }
  *(uint4*)(y1+base) = r;
}

__global__ void mx_combine(const float* __restrict__ Y2, const int* __restrict__ slot,
                           const float* __restrict__ tkw, float* __restrict__ out)
{
  int t = blockIdx.x, tid = threadIdx.x;
  int s0 = slot[t*2], s1 = slot[t*2+1];
  float w0 = tkw[t*2], w1 = tkw[t*2+1];
  const float4* r0 = (const float4*)(Y2 + (size_t)s0*H_);
  const float4* r1 = (const float4*)(Y2 + (size_t)s1*H_);
  float4* o4 = (float4*)(out + (size_t)t*H_);
  for (int i = tid; i < 512; i += 256){
    float4 a = r0[i], b = r1[i], c;
    c.x = w0*a.x + w1*b.x; c.y = w0*a.y + w1*b.y;
    c.z = w0*a.z + w1*b.z; c.w = w0*a.w + w1*b.w;
    o4[i] = c;
  }
}

extern "C" void kernel_launch(void* const* d_in, const int* in_sizes, int n_in,
                              void* d_out, int out_size, void* d_ws, size_t ws_size,
                              hipStream_t stream)
{
  (void)in_sizes; (void)n_in; (void)out_size;
  const int*   positions = (const int*)  d_in[0];
  const float* hidden    = (const float*)d_in[1];
  const float* residual  = (const float*)d_in[2];
  const float* ln1       = (const float*)d_in[3];
  const float* ln2       = (const float*)d_in[4];
  const float* wq        = (const float*)d_in[5];
  const float* wk        = (const float*)d_in[6];
  const float* wv        = (const float*)d_in[7];
  const float* wo        = (const float*)d_in[8];
  const float* gatew     = (const float*)d_in[9];
  const float* w1        = (const float*)d_in[10];
  const float* w3        = (const float*)d_in[11];
  const float* w2        = (const float*)d_in[12];
  float* outp = (float*)d_out;                 // [T*H] moe out, then [T*H] residual
  char* ws = (char*)d_ws;

  size_t off = 0;
  auto alloc = [&](size_t n){ size_t o = off; off += (n + 255) & ~(size_t)255; return o; };
  float* cosT = (float*)(ws + alloc((size_t)T_*64*4));
  float* sinT = (float*)(ws + alloc((size_t)T_*64*4));
  size_t res1_off = alloc((size_t)T_*H_*4);
  float* res1 = (float*)(ws + res1_off);
  u16*   h1h  = (u16*)  (ws + alloc((size_t)T_*H_*2));
  u16*   h1l  = (u16*)  (ws + alloc((size_t)T_*H_*2));
  float* qkvF = (float*)(ws + alloc((size_t)T_*3072*4));
  size_t qh_off = alloc((size_t)NH*T_*HD*2);
  u16*   qh   = (u16*)  (ws + qh_off);
  u16*   ql   = (u16*)  (ws + alloc((size_t)NH*T_*HD*2));
  u16*   kh   = (u16*)  (ws + alloc((size_t)NKV*T_*HD*2));
  u16*   kl   = (u16*)  (ws + alloc((size_t)NKV*T_*HD*2));
  u16*   vh   = (u16*)  (ws + alloc((size_t)NKV*T_*HD*2));
  u16*   vl   = (u16*)  (ws + alloc((size_t)NKV*T_*HD*2));
  u16*   aoh  = (u16*)  (ws + alloc((size_t)T_*2048*2));
  u16*   aol  = (u16*)  (ws + alloc((size_t)T_*2048*2));
  float* oF   = (float*)(ws + alloc((size_t)T_*H_*4));
  float* h2f  = (float*)(ws + alloc((size_t)T_*H_*4));
  u16*   h2b  = (u16*)  (ws + alloc((size_t)T_*H_*2));
  int*   meta = (int*)  (ws + alloc(32*4));
  int*   tki  = (int*)  (ws + alloc((size_t)T_*2*4));
  float* tkw  = (float*)(ws + alloc((size_t)T_*2*4));
  int*   slot = (int*)  (ws + alloc((size_t)T_*2*4));
  int*   perm = (int*)  (ws + alloc((size_t)PROWS*4));
  u16*   Y1   = (u16*)  (ws + alloc((size_t)PROWS*II_*2));
  // Y3 aliases res1..qkvF (dead before MoE GEMMs); Y2 aliases qh..oF (dead before w2 GEMM)
  u16*   Y3   = (u16*)  (ws + res1_off);
  float* Y2   = (float*)(ws + qh_off);
  // bf16 weight copies — allocated last, gated on ws_size
  u16* w1b = (u16*)(ws + alloc((size_t)NE*II_*H_*2));
  u16* w3b = (u16*)(ws + alloc((size_t)NE*II_*H_*2));
  u16* w2b = (u16*)(ws + alloc((size_t)NE*H_*II_*2));
  u16* qwh = (u16*)(ws + alloc((size_t)3072*H_*2));   // wq|wk|wv rows concat, split-hi
  u16* qwl = (u16*)(ws + alloc((size_t)3072*H_*2));
  u16* woh = (u16*)(ws + alloc((size_t)H_*H_*2));
  u16* wol = (u16*)(ws + alloc((size_t)H_*H_*2));
  bool big = ws_size >= off;

  if (big){
    // 0. weight conversions
    int n8 = NE*II_*H_/8;
    mx_cvt<<<2048, 256, 0, stream>>>(w1, w1b, n8);
    mx_cvt<<<2048, 256, 0, stream>>>(w3, w3b, n8);
    mx_cvt<<<2048, 256, 0, stream>>>(w2, w2b, n8);
    mx_cvt_split<<<512, 256, 0, stream>>>(wq, qwh,                qwl,                2048*2048/8);
    mx_cvt_split<<<512, 256, 0, stream>>>(wk, qwh + 2048*2048,    qwl + 2048*2048,    512*2048/8);
    mx_cvt_split<<<512, 256, 0, stream>>>(wv, qwh + 2560*2048,    qwl + 2560*2048,    512*2048/8);
    mx_cvt_split<<<512, 256, 0, stream>>>(wo, woh,                wol,                2048*2048/8);
  }
  // 1. RoPE tables + fused add+norm1
  mx_rope_table<<<512, 256, 0, stream>>>(positions, cosT, sinT);
  mx_addnorm<<<T_, 256, 0, stream>>>(hidden, residual, ln1, res1, h1h, h1l,
                                     nullptr, nullptr, nullptr);
  // 2. QKV projection (3-pass split)
  if (big){
    mx_gemm3g<16,24><<<384, 256, 0, stream>>>(h1h, h1l, qwh, qwl, qkvF, 3072, H_);
  } else {
    mx_gemm3<16,16><<<256, 256, 0, stream>>>(h1h, h1l, H_, wq, qkvF,        3072, H_);
    mx_gemm3<16, 4><<< 64, 256, 0, stream>>>(h1h, h1l, H_, wk, qkvF + 2048, 3072, H_);
    mx_gemm3<16, 4><<< 64, 256, 0, stream>>>(h1h, h1l, H_, wv, qkvF + 2560, 3072, H_);
  }
  // 3. RoPE apply + V transpose
  mx_rope_apply<<<dim3(T_/4, NH+NKV), 256, 0, stream>>>(qkvF, cosT, sinT, qh, ql, kh, kl);
  mx_transpose_v<<<dim3(NKV, T_/64), 256, 0, stream>>>(qkvF, vh, vl);
  // 4. attention
  mx_attn<<<dim3(T_/64, NH), 256, 0, stream>>>(qh, ql, kh, kl, vh, vl, aoh, aol);
  // 5. o_proj (3-pass split)
  if (big){
    mx_gemm3g<16,16><<<256, 256, 0, stream>>>(aoh, aol, woh, wol, oF, 2048, 2048);
  } else {
    mx_gemm3<16,16><<<256, 256, 0, stream>>>(aoh, aol, 2048, wo, oF, H_, 2048);
  }
  // 6. add + norm2 (residual output + h2 fp32 + h2 bf16); zero expert counts
  mx_addnorm<<<T_, 256, 0, stream>>>(oF, res1, ln2, outp + (size_t)T_*H_,
                                     nullptr, nullptr, h2f, h2b, meta);
  // 7. router + routing metadata
  mx_router<<<T_, 256, 0, stream>>>(h2f, gatew, meta, tki, tkw);
  mx_scan<<<1, 256, 0, stream>>>(meta, perm, big ? 7 : 8);
  mx_scatter<<<T_/256, 256, 0, stream>>>(tki, meta, perm, slot);
  // 8. MoE expert GEMMs
  if (big){
    mx_moe_w13<32><<<4096, 256, 0, stream>>>(h2b, w1b, w3b, Y1, perm, meta);
    mx_moe_w2k<16><<<2048, 256, 0, stream>>>(Y1, w2b, Y2, meta);
  } else {
    mx_moe10<1,1,64,32><<<4096, 512, 0, stream>>>(h2b, H_, w1, w3, (long long)II_*H_,
                                                  Y1, Y3, II_, H_, perm, meta);
    mx_silu<<<(PROWS*II_/8)/256, 256, 0, stream>>>(Y1, Y3);
    mx_moe10<0,0,16,16><<<1024, 512, 0, stream>>>(Y1, II_, w2, w2, (long long)H_*II_,
                                                  Y2, Y2, H_, II_, perm, meta);
  }
  // 9. combine weighted expert outputs -> out
  mx_combine<<<T_, 256, 0, stream>>>(Y2, slot, tkw, outp);
}

// Round 10
// 1083.331 us; speedup vs baseline: 1.1872x; 1.1872x over previous
//
#include <hip/hip_runtime.h>
#include <hip/hip_bf16.h>
#include <math.h>

// Mixtral decoder layer, MI355X. T=2048 H=2048 NH=16 NKV=4 HD=128 I=4096 E=8 TOPK=2.
// Pre-router path (QKV, attn, o_proj): 3-pass bf16-split MFMA (~fp32 accurate) so the
// router top-k matches the fp32 reference; MoE expert path is plain bf16.
// R10: attn single-buffered 80KB LDS (2 blocks/CU -> 2 waves/SIMD latency hiding);
// w13/w2k m97-style; QKV/o_proj via pre-split bf16 weights (gemm3g); weights cvt'd once.

#define T_  2048
#define H_  2048
#define NH  16
#define NKV 4
#define HD  128
#define II_ 4096
#define NE  8
#define EPS 1e-5f
#define PROWS 6144   // padded permuted rows

typedef __bf16 bf16x8 __attribute__((ext_vector_type(8)));
typedef float  f32x4  __attribute__((ext_vector_type(4)));
typedef unsigned short u16;

__device__ __forceinline__ u16 f2b(float f){ __bf16 b = (__bf16)f; return __builtin_bit_cast(u16, b); }
__device__ __forceinline__ float b2f(u16 u){ return (float)__builtin_bit_cast(__bf16, u); }

__device__ __forceinline__ void gll16(const void* g, void* l){
  __builtin_amdgcn_global_load_lds(
      (const __attribute__((address_space(1))) unsigned int*)g,
      (__attribute__((address_space(3))) unsigned int*)l, 16, 0, 0);
}

__device__ __forceinline__ bf16x8 cvt8(f32x4 a, f32x4 b){
  uint4 u;
  u.x = (unsigned)f2b(a[0]) | ((unsigned)f2b(a[1])<<16);
  u.y = (unsigned)f2b(a[2]) | ((unsigned)f2b(a[3])<<16);
  u.z = (unsigned)f2b(b[0]) | ((unsigned)f2b(b[1])<<16);
  u.w = (unsigned)f2b(b[2]) | ((unsigned)f2b(b[3])<<16);
  return __builtin_bit_cast(bf16x8, u);
}

// ---------------- fp32 -> packed bf16 streaming conversion ----------------
__global__ __launch_bounds__(256) void mx_cvt(const float* __restrict__ s,
                                              u16* __restrict__ d, int n8)
{
  int i = blockIdx.x*256 + threadIdx.x;
  int stride = gridDim.x*256;
  for (; i < n8; i += stride){
    const f32x4* p = (const f32x4*)s + 2*(size_t)i;
    f32x4 a = p[0], b = p[1];
    uint4 u;
    u.x = (unsigned)f2b(a[0]) | ((unsigned)f2b(a[1])<<16);
    u.y = (unsigned)f2b(a[2]) | ((unsigned)f2b(a[3])<<16);
    u.z = (unsigned)f2b(b[0]) | ((unsigned)f2b(b[1])<<16);
    u.w = (unsigned)f2b(b[2]) | ((unsigned)f2b(b[3])<<16);
    ((uint4*)d)[i] = u;
  }
}

// ---------------- fp32 -> split (hi, lo) bf16 conversion ----------------
__global__ __launch_bounds__(256) void mx_cvt_split(const float* __restrict__ s,
                                                    u16* __restrict__ hi,
                                                    u16* __restrict__ lo, int n8)
{
  int i = blockIdx.x*256 + threadIdx.x;
  int stride = gridDim.x*256;
  for (; i < n8; i += stride){
    const f32x4* p = (const f32x4*)s + 2*(size_t)i;
    f32x4 a = p[0], b = p[1];
    uint4 uh, ul;
    u16 h0,h1,h2,h3;
    h0=f2b(a[0]); h1=f2b(a[1]); h2=f2b(a[2]); h3=f2b(a[3]);
    uh.x = (unsigned)h0 | ((unsigned)h1<<16);
    uh.y = (unsigned)h2 | ((unsigned)h3<<16);
    ul.x = (unsigned)f2b(a[0]-b2f(h0)) | ((unsigned)f2b(a[1]-b2f(h1))<<16);
    ul.y = (unsigned)f2b(a[2]-b2f(h2)) | ((unsigned)f2b(a[3]-b2f(h3))<<16);
    h0=f2b(b[0]); h1=f2b(b[1]); h2=f2b(b[2]); h3=f2b(b[3]);
    uh.z = (unsigned)h0 | ((unsigned)h1<<16);
    uh.w = (unsigned)h2 | ((unsigned)h3<<16);
    ul.z = (unsigned)f2b(b[0]-b2f(h0)) | ((unsigned)f2b(b[1]-b2f(h1))<<16);
    ul.w = (unsigned)f2b(b[2]-b2f(h2)) | ((unsigned)f2b(b[3]-b2f(h3))<<16);
    ((uint4*)hi)[i] = uh;
    ((uint4*)lo)[i] = ul;
  }
}

// ---------------- RoPE cos/sin table (double-precision inv_freq) ----------------
__global__ void mx_rope_table(const int* __restrict__ pos, float* __restrict__ cosT,
                              float* __restrict__ sinT)
{
  int i = blockIdx.x*256 + threadIdx.x;            // T*64
  int t = i >> 6, d = i & 63;
  float inv = (float)exp(-((double)d/64.0) * 9.210340371976184); // 10000^{-d/64}
  float f = (float)pos[t] * inv;
  cosT[i] = cosf(f); sinT[i] = sinf(f);
}

// ---------------- fused add + RMSNorm (writes several output forms) ----------------
__global__ __launch_bounds__(256) void mx_addnorm(
    const float* __restrict__ a, const float* __restrict__ b,
    const float* __restrict__ gam, float* __restrict__ res_out,
    u16* __restrict__ hi, u16* __restrict__ lo,
    float* __restrict__ hf, u16* __restrict__ hbf, int* __restrict__ mz)
{
  int t = blockIdx.x, tid = threadIdx.x;
  if (mz && t == 0 && tid < 8) mz[tid] = 0;
  const float4* A4 = (const float4*)a + (size_t)t*512;
  const float4* B4 = (const float4*)b + (size_t)t*512;
  float4 va = A4[tid], vb = B4[tid];
  float4 x0; x0.x=va.x+vb.x; x0.y=va.y+vb.y; x0.z=va.z+vb.z; x0.w=va.w+vb.w;
  va = A4[tid+256]; vb = B4[tid+256];
  float4 x1; x1.x=va.x+vb.x; x1.y=va.y+vb.y; x1.z=va.z+vb.z; x1.w=va.w+vb.w;
  float ss = x0.x*x0.x + x0.y*x0.y + x0.z*x0.z + x0.w*x0.w
           + x1.x*x1.x + x1.y*x1.y + x1.z*x1.z + x1.w*x1.w;
  #pragma unroll
  for (int d=32; d; d>>=1) ss += __shfl_down(ss, d);
  __shared__ float red[4];
  if ((tid&63)==0) red[tid>>6] = ss;
  __syncthreads();
  ss = red[0]+red[1]+red[2]+red[3];
  float scale = rsqrtf(ss * (1.f/2048.f) + EPS);
  float4* R4 = (float4*)res_out + (size_t)t*512;
  R4[tid] = x0; R4[tid+256] = x1;
  const float4* G4p = (const float4*)gam;
  float4 g0 = G4p[tid], g1 = G4p[tid+256];
  float4 y0; y0.x=x0.x*scale*g0.x; y0.y=x0.y*scale*g0.y; y0.z=x0.z*scale*g0.z; y0.w=x0.w*scale*g0.w;
  float4 y1; y1.x=x1.x*scale*g1.x; y1.y=x1.y*scale*g1.y; y1.z=x1.z*scale*g1.z; y1.w=x1.w*scale*g1.w;
  if (hf){ float4* H4 = (float4*)hf + (size_t)t*512; H4[tid]=y0; H4[tid+256]=y1; }
  if (hi){
    ushort4 uh, ul;
    uh.x=f2b(y0.x); ul.x=f2b(y0.x-b2f(uh.x));
    uh.y=f2b(y0.y); ul.y=f2b(y0.y-b2f(uh.y));
    uh.z=f2b(y0.z); ul.z=f2b(y0.z-b2f(uh.z));
    uh.w=f2b(y0.w); ul.w=f2b(y0.w-b2f(uh.w));
    ((ushort4*)hi)[(size_t)t*512 + tid] = uh; ((ushort4*)lo)[(size_t)t*512 + tid] = ul;
    uh.x=f2b(y1.x); ul.x=f2b(y1.x-b2f(uh.x));
    uh.y=f2b(y1.y); ul.y=f2b(y1.y-b2f(uh.y));
    uh.z=f2b(y1.z); ul.z=f2b(y1.z-b2f(uh.z));
    uh.w=f2b(y1.w); ul.w=f2b(y1.w-b2f(uh.w));
    ((ushort4*)hi)[(size_t)t*512 + tid+256] = uh; ((ushort4*)lo)[(size_t)t*512 + tid+256] = ul;
  }
  if (hbf){
    ushort4 u0; u0.x=f2b(y0.x); u0.y=f2b(y0.y); u0.z=f2b(y0.z); u0.w=f2b(y0.w);
    ushort4 u1; u1.x=f2b(y1.x); u1.y=f2b(y1.y); u1.z=f2b(y1.z); u1.w=f2b(y1.w);
    ((ushort4*)hbf)[(size_t)t*512 + tid] = u0; ((ushort4*)hbf)[(size_t)t*512 + tid+256] = u1;
  }
}

// ------- 3-pass split GEMM, gll16 m97 skeleton: C = A(hi,lo) x B(hi,lo)^T, fp32 out -------
template<int NX, int NY>
__global__ __launch_bounds__(256,2) void mx_gemm3g(
    const u16* __restrict__ Ah, const u16* __restrict__ Al,
    const u16* __restrict__ Bh, const u16* __restrict__ Bl,
    float* __restrict__ C, int ldc, int K)
{
  __shared__ u16 AhS[128*64], AlS[128*64], BhS[128*64], BlS[128*64];
  int bid = blockIdx.x;
  int xcd = bid & 7, j = bid >> 3;
  int x = j % NX, p = j / NX;
  int y = xcd + 8*p;
  int m0 = x*128, n0 = y*128;
  int tid = threadIdx.x;
  int w = tid>>6, lane = tid&63, wr = w>>1, wc = w&1, g = lane>>4, lr = lane&15;
  f32x4 acc[4][4];
  #pragma unroll
  for (int fm=0;fm<4;fm++)
    #pragma unroll
    for (int fn=0;fn<4;fn++) acc[fm][fn] = (f32x4){0.f,0.f,0.f,0.f};

  for (int k0 = 0; k0 < K; k0 += 64) {
    #pragma unroll
    for (int i=0;i<4;i++){
      int c = i*256 + tid, r = c>>3, ch = c&7;
      int sw = ((ch ^ (r&7))<<3);
      int db = (i*256 + w*64)<<3;
      gll16(Ah + (size_t)(m0+r)*K + k0 + sw, &AhS[db]);
      gll16(Al + (size_t)(m0+r)*K + k0 + sw, &AlS[db]);
      gll16(Bh + (size_t)(n0+r)*K + k0 + sw, &BhS[db]);
      gll16(Bl + (size_t)(n0+r)*K + k0 + sw, &BlS[db]);
    }
    __syncthreads();
    #pragma unroll
    for (int kk=0;kk<2;kk++){
      bf16x8 ah[4], al[4], bh[4], bl[4];
      #pragma unroll
      for (int fm=0;fm<4;fm++){
        int r = wr*64 + fm*16 + lr;
        int ch = ((kk<<2)+g) ^ (r&7);
        ah[fm] = *(const bf16x8*)(&AhS[(r<<6)+(ch<<3)]);
        al[fm] = *(const bf16x8*)(&AlS[(r<<6)+(ch<<3)]);
      }
      #pragma unroll
      for (int fn=0;fn<4;fn++){
        int r = wc*64 + fn*16 + lr;
        int ch = ((kk<<2)+g) ^ (r&7);
        bh[fn] = *(const bf16x8*)(&BhS[(r<<6)+(ch<<3)]);
        bl[fn] = *(const bf16x8*)(&BlS[(r<<6)+(ch<<3)]);
      }
      __builtin_amdgcn_s_setprio(1);
      #pragma unroll
      for (int fm=0;fm<4;fm++)
        #pragma unroll
        for (int fn=0;fn<4;fn++){
          acc[fm][fn] = __builtin_amdgcn_mfma_f32_16x16x32_bf16(ah[fm], bh[fn], acc[fm][fn],0,0,0);
          acc[fm][fn] = __builtin_amdgcn_mfma_f32_16x16x32_bf16(ah[fm], bl[fn], acc[fm][fn],0,0,0);
          acc[fm][fn] = __builtin_amdgcn_mfma_f32_16x16x32_bf16(al[fm], bh[fn], acc[fm][fn],0,0,0);
        }
      __builtin_amdgcn_s_setprio(0);
    }
    __syncthreads();
  }
  #pragma unroll
  for (int fm=0;fm<4;fm++)
    #pragma unroll
    for (int fn=0;fn<4;fn++)
      #pragma unroll
      for (int i=0;i<4;i++){
        size_t rg = (size_t)(m0 + wr*64 + fm*16 + g*4 + i);
        int cg = n0 + wc*64 + fn*16 + lr;
        C[rg*ldc + cg] = acc[fm][fn][i];
      }
}

// ------------- 3-pass split-bf16 GEMM (fallback, fp32 B in-loop) -------------
template<int NX, int NY>
__global__ __launch_bounds__(256) void mx_gemm3(
    const u16* __restrict__ Ah, const u16* __restrict__ Al, int lda,
    const float* __restrict__ B,
    float* __restrict__ C, int ldc, int K)
{
  const int LDT = 72;
  __shared__ u16 Ash[128*LDT], Asl[128*LDT], Bsh[128*LDT], Bsl[128*LDT];
  int bid = blockIdx.x, x, y;
  if constexpr ((NY & 7) == 0) {
    int xcd = bid & 7, j = bid >> 3;
    x = j % NX; int p = j / NX;
    y = xcd + 8*p;
  } else { x = bid % NX; y = bid / NX; }
  int m0 = x*128, n0 = y*128;
  int tid = threadIdx.x;
  int w = tid>>6, lane = tid&63, wr = w>>1, wc = w&1, g = lane>>4, lr = lane&15;
  f32x4 acc[4][4];
  #pragma unroll
  for (int fm=0;fm<4;fm++)
    #pragma unroll
    for (int fn=0;fn<4;fn++) acc[fm][fn] = (f32x4){0.f,0.f,0.f,0.f};
  for (int k0 = 0; k0 < K; k0 += 64) {
    #pragma unroll
    for (int i=0;i<4;i++){
      int c = i*256 + tid, r = c>>3, ch = c&7;
      *(uint4*)(&Ash[r*LDT + ch*8]) = *(const uint4*)(Ah + (size_t)(m0+r)*lda + k0 + ch*8);
      *(uint4*)(&Asl[r*LDT + ch*8]) = *(const uint4*)(Al + (size_t)(m0+r)*lda + k0 + ch*8);
    }
    #pragma unroll
    for (int i=0;i<8;i++){
      int f = i*256 + tid, r = f>>4, c4 = f&15;
      float4 v = *(const float4*)(B + (size_t)(n0+r)*K + k0 + c4*4);
      ushort4 hv, lv;
      hv.x=f2b(v.x); lv.x=f2b(v.x-b2f(hv.x));
      hv.y=f2b(v.y); lv.y=f2b(v.y-b2f(hv.y));
      hv.z=f2b(v.z); lv.z=f2b(v.z-b2f(hv.z));
      hv.w=f2b(v.w); lv.w=f2b(v.w-b2f(hv.w));
      *(ushort4*)(&Bsh[r*LDT + c4*4]) = hv;
      *(ushort4*)(&Bsl[r*LDT + c4*4]) = lv;
    }
    __syncthreads();
    #pragma unroll
    for (int kk=0;kk<2;kk++){
      bf16x8 ah[4], al[4], bh[4], bl[4];
      #pragma unroll
      for (int fm=0;fm<4;fm++){
        int r = wr*64 + fm*16 + lr;
        ah[fm] = *(const bf16x8*)(&Ash[r*LDT + kk*32 + g*8]);
        al[fm] = *(const bf16x8*)(&Asl[r*LDT + kk*32 + g*8]);
      }
      #pragma unroll
      for (int fn=0;fn<4;fn++){
        int r = wc*64 + fn*16 + lr;
        bh[fn] = *(const bf16x8*)(&Bsh[r*LDT + kk*32 + g*8]);
        bl[fn] = *(const bf16x8*)(&Bsl[r*LDT + kk*32 + g*8]);
      }
      __builtin_amdgcn_s_setprio(1);
      #pragma unroll
      for (int fm=0;fm<4;fm++)
        #pragma unroll
        for (int fn=0;fn<4;fn++){
          acc[fm][fn] = __builtin_amdgcn_mfma_f32_16x16x32_bf16(ah[fm], bh[fn], acc[fm][fn],0,0,0);
          acc[fm][fn] = __builtin_amdgcn_mfma_f32_16x16x32_bf16(ah[fm], bl[fn], acc[fm][fn],0,0,0);
          acc[fm][fn] = __builtin_amdgcn_mfma_f32_16x16x32_bf16(al[fm], bh[fn], acc[fm][fn],0,0,0);
        }
      __builtin_amdgcn_s_setprio(0);
    }
    __syncthreads();
  }
  #pragma unroll
  for (int fm=0;fm<4;fm++)
    #pragma unroll
    for (int fn=0;fn<4;fn++)
      #pragma unroll
      for (int i=0;i<4;i++){
        size_t rg = (size_t)(m0 + wr*64 + fm*16 + g*4 + i);
        int cg = n0 + wc*64 + fn*16 + lr;
        C[rg*ldc + cg] = acc[fm][fn][i];
      }
}

// ------------- MoE w1+w3 fused GEMM + silu epilogue (all-bf16, m97-style) -------------
template<int NY>
__global__ __launch_bounds__(256,2) void mx_moe_w13(
    const u16* __restrict__ A,
    const u16* __restrict__ B1, const u16* __restrict__ B3,
    u16* __restrict__ Y,
    const int* __restrict__ row_map, const int* __restrict__ meta)
{
  __shared__ u16 As[128*64], B1s[128*64], B3s[128*64];
  int bid = blockIdx.x;
  int xcd = bid & 7, j = bid >> 3;
  int x = j & 15, p = j >> 4;
  int panel = xcd + 8*p;                 // < NE*NY
  int e = panel / NY, y = panel % NY;
  if (x >= meta[16+e]) return;
  int rowbase = meta[8+e] + (x<<7);
  const u16* B1p = B1 + ((size_t)e*II_ + y*128)*H_;
  const u16* B3p = B3 + ((size_t)e*II_ + y*128)*H_;
  int tid = threadIdx.x;
  int w = tid>>6, lane = tid&63, wr = w>>1, wc = w&1, g = lane>>4, lr = lane&15;

  f32x4 acc1[4][4], acc3[4][4];
  #pragma unroll
  for (int fm=0;fm<4;fm++)
    #pragma unroll
    for (int fn=0;fn<4;fn++){ acc1[fm][fn]=(f32x4){0,0,0,0}; acc3[fm][fn]=(f32x4){0,0,0,0}; }

  for (int k0 = 0; k0 < H_; k0 += 64) {
    #pragma unroll
    for (int i=0;i<4;i++){
      int c = i*256 + tid, r = c>>3, ch = c&7;
      int sw = (ch ^ (r&7))<<3;
      int db = (i*256 + w*64)<<3;
      int grow = row_map[rowbase + r];
      gll16(A   + (size_t)grow*H_ + k0 + sw, &As[db]);
      gll16(B1p + (size_t)r*H_    + k0 + sw, &B1s[db]);
      gll16(B3p + (size_t)r*H_    + k0 + sw, &B3s[db]);
    }
    __syncthreads();
    #pragma unroll
    for (int kk=0;kk<2;kk++){
      bf16x8 af[4], b1f[4], b3f[4];
      #pragma unroll
      for (int fm=0;fm<4;fm++){
        int r = wr*64 + fm*16 + lr;
        int ch = ((kk<<2)+g) ^ (r&7);
        af[fm] = *(const bf16x8*)(&As[(r<<6)+(ch<<3)]);
      }
      #pragma unroll
      for (int fn=0;fn<4;fn++){
        int r = wc*64 + fn*16 + lr;
        int ch = ((kk<<2)+g) ^ (r&7);
        b1f[fn] = *(const bf16x8*)(&B1s[(r<<6)+(ch<<3)]);
        b3f[fn] = *(const bf16x8*)(&B3s[(r<<6)+(ch<<3)]);
      }
      __builtin_amdgcn_s_setprio(1);
      #pragma unroll
      for (int fm=0;fm<4;fm++)
        #pragma unroll
        for (int fn=0;fn<4;fn++){
          acc1[fm][fn] = __builtin_amdgcn_mfma_f32_16x16x32_bf16(af[fm], b1f[fn], acc1[fm][fn],0,0,0);
          acc3[fm][fn] = __builtin_amdgcn_mfma_f32_16x16x32_bf16(af[fm], b3f[fn], acc3[fm][fn],0,0,0);
        }
      __builtin_amdgcn_s_setprio(0);
    }
    __syncthreads();
  }
  int n0 = y*128 + wc*64;
  #pragma unroll
  for (int fm=0;fm<4;fm++)
    #pragma unroll
    for (int fn=0;fn<4;fn++)
      #pragma unroll
      for (int i=0;i<4;i++){
        size_t rg = (size_t)(rowbase + wr*64 + fm*16 + g*4 + i);
        int cg = n0 + fn*16 + lr;
        float gg = acc1[fm][fn][i], uu = acc3[fm][fn][i];
        float sg = gg / (1.f + __expf(-gg));
        Y[rg*II_ + cg] = f2b(sg * uu);
      }
}

// ------------- MoE w2 GEMM (all-bf16, m97-style): Y2 = Y . w2^T -------------
template<int NY>
__global__ __launch_bounds__(256,2) void mx_moe_w2k(
    const u16* __restrict__ A,       // Y bf16 [PROWS][II_]
    const u16* __restrict__ B,       // w2b bf16 [E][H_][II_]
    float* __restrict__ C,           // Y2 fp32 [PROWS][H_]
    const int* __restrict__ meta)
{
  __shared__ u16 As[128*64], Bs[128*64];
  int bid = blockIdx.x;
  int xcd = bid & 7, j = bid >> 3;
  int x = j & 15, p = j >> 4;
  int panel = xcd + 8*p;                 // < NE*NY
  int e = panel / NY, y = panel % NY;
  if (x >= meta[16+e]) return;
  int rowbase = meta[8+e] + (x<<7);
  const u16* Bp = B + ((size_t)e*H_ + y*128)*II_;
  int tid = threadIdx.x;
  int w = tid>>6, lane = tid&63, wr = w>>1, wc = w&1, g = lane>>4, lr = lane&15;

  f32x4 acc[4][4];
  #pragma unroll
  for (int fm=0;fm<4;fm++)
    #pragma unroll
    for (int fn=0;fn<4;fn++) acc[fm][fn] = (f32x4){0,0,0,0};

  for (int k0 = 0; k0 < II_; k0 += 64) {
    #pragma unroll
    for (int i=0;i<4;i++){
      int c = i*256 + tid, r = c>>3, ch = c&7;
      int sw = (ch ^ (r&7))<<3;
      int db = (i*256 + w*64)<<3;
      gll16(A  + (size_t)(rowbase + r)*II_ + k0 + sw, &As[db]);
      gll16(Bp + (size_t)r*II_             + k0 + sw, &Bs[db]);
    }
    __syncthreads();
    #pragma unroll
    for (int kk=0;kk<2;kk++){
      bf16x8 af[4], bf[4];
      #pragma unroll
      for (int fm=0;fm<4;fm++){
        int r = wr*64 + fm*16 + lr;
        int ch = ((kk<<2)+g) ^ (r&7);
        af[fm] = *(const bf16x8*)(&As[(r<<6)+(ch<<3)]);
      }
      #pragma unroll
      for (int fn=0;fn<4;fn++){
        int r = wc*64 + fn*16 + lr;
        int ch = ((kk<<2)+g) ^ (r&7);
        bf[fn] = *(const bf16x8*)(&Bs[(r<<6)+(ch<<3)]);
      }
      __builtin_amdgcn_s_setprio(1);
      #pragma unroll
      for (int fm=0;fm<4;fm++)
        #pragma unroll
        for (int fn=0;fn<4;fn++)
          acc[fm][fn] = __builtin_amdgcn_mfma_f32_16x16x32_bf16(af[fm], bf[fn], acc[fm][fn],0,0,0);
      __builtin_amdgcn_s_setprio(0);
    }
    __syncthreads();
  }
  int n0 = y*128 + wc*64;
  #pragma unroll
  for (int fm=0;fm<4;fm++)
    #pragma unroll
    for (int fn=0;fn<4;fn++)
      #pragma unroll
      for (int i=0;i<4;i++){
        size_t rg = (size_t)(rowbase + wr*64 + fm*16 + g*4 + i);
        int cg = n0 + fn*16 + lr;
        C[rg*H_ + cg] = acc[fm][fn][i];
      }
}

// ------------- MoE GEMM fallback (R5): BM=256 BN=128 BK=32, fp32 B direct -------------
template<int GATHER, int CBF16, int NYT, int SPLITY>
__global__ __launch_bounds__(512,4) void mx_moe10(
    const u16* __restrict__ A, int lda,
    const float* __restrict__ B1, const float* __restrict__ B2, long long strideB,
    void* __restrict__ C1v, void* __restrict__ C2v, int ldc, int K,
    const int* __restrict__ row_map, const int* __restrict__ meta)
{
  __shared__ u16 AS[3][256*32];
  int bid = blockIdx.x;
  int xcd = bid & 7, j = bid >> 3;
  int x = j & 7, q = j >> 3;
  int panel = xcd + 8*q;
  int e = panel / NYT, y = panel % NYT;
  if (x >= meta[16+e]) return;
  int rowbase = meta[8+e] + x*256;
  int yy = (y < SPLITY) ? y : y - SPLITY;
  const float* Bp = ((y < SPLITY) ? B1 : B2) + (long long)e*strideB + (size_t)(yy*128)*K;
  void* Cv = (y < SPLITY) ? C1v : C2v;
  int tid = threadIdx.x;
  int w = tid>>6, lane = tid&63, wr = w>>2, wc = w&3, g = lane>>4, lr = lane&15;
  const u16 *srcA0, *srcA1;
  {
    int c0 = tid,     r0 = c0>>2;
    int c1 = 512+tid, r1 = c1>>2;
    int s0 = (c0&3) ^ ((r0>>1)&3);
    int s1 = (c1&3) ^ ((r1>>1)&3);
    int w0 = GATHER ? row_map[rowbase+r0] : (rowbase+r0);
    int w1r = GATHER ? row_map[rowbase+r1] : (rowbase+r1);
    srcA0 = A + (size_t)w0*lda + s0*8;
    srcA1 = A + (size_t)w1r*lda + s1*8;
  }
  const float *srcB0, *srcB1;
  {
    int r0 = wc*32 + lr;
    int r1 = wc*32 + 16 + lr;
    srcB0 = Bp + (size_t)r0*K + g*8;
    srcB1 = Bp + (size_t)r1*K + g*8;
  }
  f32x4 acc[8][2];
  #pragma unroll
  for (int fm=0;fm<8;fm++){ acc[fm][0]=(f32x4){0,0,0,0}; acc[fm][1]=(f32x4){0,0,0,0}; }
  f32x4 e0,e1,e2,e3, o0,o1,o2,o3;
  u16 *pa0=&AS[0][0], *pa1=&AS[1][0], *pa2=&AS[2][0];
  int nt = K >> 5;
  auto stageA = [&](u16* as, int k0){
    gll16(srcA0 + k0, as + (w*64)*8);
    gll16(srcA1 + k0, as + (512 + w*64)*8);
  };
  auto issueB = [&](int k0, f32x4& b0, f32x4& b1, f32x4& b2, f32x4& b3){
    b0 = *(const f32x4*)(srcB0 + k0);
    b1 = *(const f32x4*)(srcB0 + k0 + 4);
    b2 = *(const f32x4*)(srcB1 + k0);
    b3 = *(const f32x4*)(srcB1 + k0 + 4);
  };
  auto compute = [&](const u16* as, f32x4 b0, f32x4 b1, f32x4 b2, f32x4 b3){
    bf16x8 bf0 = cvt8(b0,b1), bf1 = cvt8(b2,b3);
    __builtin_amdgcn_s_setprio(1);
    #pragma unroll
    for (int fm=0;fm<8;fm++){
      int r = wr*128 + fm*16 + lr;
      int ch = g ^ ((r>>1)&3);
      bf16x8 af = *(const bf16x8*)(as + r*32 + ch*8);
      acc[fm][0] = __builtin_amdgcn_mfma_f32_16x16x32_bf16(af, bf0, acc[fm][0],0,0,0);
      acc[fm][1] = __builtin_amdgcn_mfma_f32_16x16x32_bf16(af, bf1, acc[fm][1],0,0,0);
    }
    __builtin_amdgcn_s_setprio(0);
  };
  auto rot = [&](){ u16* t0=pa0; pa0=pa1; pa1=pa2; pa2=t0; };
  auto kclamp = [&](int t){ return (t < nt ? t : 0) << 5; };
  issueB(0, e0,e1,e2,e3);
  asm volatile("" ::: "memory");
  stageA(pa0, 0);
  asm volatile("" ::: "memory");
  stageA(pa1, kclamp(1));
  for (int t=0; t<nt; t+=2){
    asm volatile("s_waitcnt vmcnt(2)" ::: "memory");
    __builtin_amdgcn_s_barrier();
    issueB(kclamp(t+1), o0,o1,o2,o3);
    asm volatile("" ::: "memory");
    stageA(pa2, kclamp(t+2));
    compute(pa0, e0,e1,e2,e3);
    rot();
    asm volatile("s_waitcnt vmcnt(2)" ::: "memory");
    __builtin_amdgcn_s_barrier();
    issueB(kclamp(t+2), e0,e1,e2,e3);
    asm volatile("" ::: "memory");
    stageA(pa2, kclamp(t+3));
    compute(pa0, o0,o1,o2,o3);
    rot();
  }
  int n0 = yy*128 + wc*32;
  #pragma unroll
  for (int fm=0;fm<8;fm++)
    #pragma unroll
    for (int fn=0;fn<2;fn++)
      #pragma unroll
      for (int i=0;i<4;i++){
        size_t rg = (size_t)(rowbase + wr*128 + fm*16 + g*4 + i);
        int cg = n0 + fn*16 + lr;
        if (CBF16) ((u16*)Cv)[rg*ldc + cg] = f2b(acc[fm][fn][i]);
        else       ((float*)Cv)[rg*ldc + cg] = acc[fm][fn][i];
      }
}

// ---------------- RoPE apply: qkv fp32 -> split-bf16 Q [h][t][d], K [kv][t][d] ----------------
__global__ __launch_bounds__(256) void mx_rope_apply(const float* __restrict__ qkv,
    const float* __restrict__ cosT, const float* __restrict__ sinT,
    u16* __restrict__ qh, u16* __restrict__ ql, u16* __restrict__ kh, u16* __restrict__ kl)
{
  int t = blockIdx.x*4 + (threadIdx.x>>6);
  int hh = blockIdx.y, d = threadIdx.x & 63;
  const float* row = qkv + (size_t)t*3072;
  float c = cosT[t*64+d], s = sinT[t*64+d];
  float x1, x2; size_t base; u16 *oh, *ol;
  if (hh < NH){ x1 = row[hh*HD+d]; x2 = row[hh*HD+d+64];
     base = ((size_t)hh*T_ + t)*HD; oh = qh; ol = ql; }
  else { int kvh = hh-NH; x1 = row[2048 + kvh*HD + d]; x2 = row[2048 + kvh*HD + d + 64];
     base = ((size_t)kvh*T_ + t)*HD; oh = kh; ol = kl; }
  float o1 = x1*c - x2*s, o2 = x2*c + x1*s;
  u16 a = f2b(o1); oh[base+d]    = a; ol[base+d]    = f2b(o1 - b2f(a));
  u16 b = f2b(o2); oh[base+d+64] = b; ol[base+d+64] = f2b(o2 - b2f(b));
}

// ---------------- V transpose: qkv fp32 -> split-bf16 V^T [kv][d][t] ----------------
__global__ void mx_transpose_v(const float* __restrict__ qkv,
                               u16* __restrict__ vh, u16* __restrict__ vl)
{
  __shared__ float tile[64][132];
  int kv = blockIdx.x, t0 = blockIdx.y*64, tid = threadIdx.x;
  #pragma unroll
  for (int it=0; it<32; ++it){
    int idx = it*256 + tid; int r = idx>>7, d = idx&127;
    tile[r][d] = qkv[(size_t)(t0+r)*3072 + 2560 + kv*HD + d];
  }
  __syncthreads();
  #pragma unroll
  for (int it=0; it<32; ++it){
    int idx = it*256 + tid; int d = idx>>6, j = idx&63;
    float x = tile[j][d];
    u16 a = f2b(x);
    size_t o = ((size_t)kv*HD + d)*T_ + t0 + j;
    vh[o] = a; vl[o] = f2b(x - b2f(a));
  }
}

// ---------------- flash attention, causal GQA, 3-pass split-bf16 ----------------
// Single-buffered 80KB LDS (K/V hi+lo + P) -> 2 blocks/CU; per-kt vmcnt(0)+barrier
// drains hidden by the co-resident block (m97/m114 mechanism).
__global__ __launch_bounds__(256) void mx_attn(
  const u16* __restrict__ qh_, const u16* __restrict__ ql_,
  const u16* __restrict__ kh_, const u16* __restrict__ kl_,
  const u16* __restrict__ vh_, const u16* __restrict__ vl_,
  u16* __restrict__ oh_, u16* __restrict__ ol_)
{
  int h = blockIdx.y, kvh = h >> 2;
  int qt = (h & 8) ? (31 - (int)blockIdx.x) : (int)blockIdx.x;
  int tid = threadIdx.x, w = tid>>6, lane = tid&63, g = lane>>4, lr = lane&15;
  int q0 = qt*64 + w*16;
  __shared__ u16 KV[4][8192];             // [Kh,Kl,Vh,Vl] = 64 KB (single buffer)
  __shared__ u16 Ph[4][1024], Pl[4][1024];  // 16 KB

  bf16x8 qfh[4], qfl[4];
  const u16* qrh = qh_ + ((size_t)h*T_ + q0 + lr)*HD;
  const u16* qrl = ql_ + ((size_t)h*T_ + q0 + lr)*HD;
  #pragma unroll
  for (int kk=0;kk<4;kk++){
    qfh[kk] = *(const bf16x8*)(qrh + kk*32 + g*8);
    qfl[kk] = *(const bf16x8*)(qrl + kk*32 + g*8);
  }
  f32x4 o[8];
  #pragma unroll
  for (int nf=0;nf<8;nf++) o[nf] = (f32x4){0.f,0.f,0.f,0.f};
  float mreg[4] = {-3e38f,-3e38f,-3e38f,-3e38f}, lsum[4] = {0.f,0.f,0.f,0.f};

  const u16* kbase = kh_ + (size_t)kvh*T_*HD;
  const u16* lbase = kl_ + (size_t)kvh*T_*HD;
  const u16* vbase = vh_ + (size_t)kvh*HD*T_;
  const u16* wbase = vl_ + (size_t)kvh*HD*T_;

  auto stage = [&](int kvb){
    #pragma unroll
    for (int i=0;i<4;i++){
      int cb = i*256 + w*64;            // wave-uniform chunk base
      int c  = cb + lane;
      int kr = c>>4, kc = ((c&15) ^ (kr&7))<<3;
      gll16(kbase + (size_t)(kvb+kr)*HD + kc, &KV[0][cb*8]);
      gll16(lbase + (size_t)(kvb+kr)*HD + kc, &KV[1][cb*8]);
      int vr = c>>3, vc = ((c&7) ^ (vr&7))<<3;
      gll16(vbase + (size_t)vr*T_ + kvb + vc, &KV[2][cb*8]);
      gll16(wbase + (size_t)vr*T_ + kvb + vc, &KV[3][cb*8]);
    }
  };

  for (int kt = 0; kt <= qt; ++kt) {
    int kvb = kt*64;
    stage(kvb);
    asm volatile("s_waitcnt vmcnt(0)" ::: "memory");
    __builtin_amdgcn_s_barrier();

    // ---- QK^T (3-pass split) from LDS ----
    f32x4 s[4];
    #pragma unroll
    for (int nf=0;nf<4;nf++) s[nf] = (f32x4){0.f,0.f,0.f,0.f};
    __builtin_amdgcn_s_setprio(1);
    #pragma unroll
    for (int nf=0; nf<4; nf++){
      int row = nf*16 + lr;
      #pragma unroll
      for (int kk=0;kk<4;kk++){
        int off = row*128 + ((((kk<<2)+g) ^ (lr&7))<<3);
        bf16x8 kf = *(const bf16x8*)(&KV[0][off]);
        bf16x8 kg = *(const bf16x8*)(&KV[1][off]);
        s[nf] = __builtin_amdgcn_mfma_f32_16x16x32_bf16(qfh[kk], kf, s[nf],0,0,0);
        s[nf] = __builtin_amdgcn_mfma_f32_16x16x32_bf16(qfh[kk], kg, s[nf],0,0,0);
        s[nf] = __builtin_amdgcn_mfma_f32_16x16x32_bf16(qfl[kk], kf, s[nf],0,0,0);
      }
    }
    __builtin_amdgcn_s_setprio(0);

    // ---- online softmax ----
    float sv[4][4], pm[4];
    #pragma unroll
    for (int i=0;i<4;i++) pm[i] = -3e38f;
    bool diag = (kt == qt);
    #pragma unroll
    for (int nf=0;nf<4;nf++)
      #pragma unroll
      for (int i=0;i<4;i++){
        float v = s[nf][i] * 0.08838834764831845f;
        if (diag && (kvb + nf*16 + lr > q0 + g*4 + i)) v = -1e30f;
        sv[nf][i] = v;
        pm[i] = fmaxf(pm[i], v);
      }
    #pragma unroll
    for (int i=0;i<4;i++)
      #pragma unroll
      for (int d=1; d<16; d<<=1) pm[i] = fmaxf(pm[i], __shfl_xor(pm[i], d));
    float sf[4], psum[4];
    #pragma unroll
    for (int i=0;i<4;i++){
      float nm = fmaxf(mreg[i], pm[i]);
      sf[i] = __expf(mreg[i] - nm);
      mreg[i] = nm; psum[i] = 0.f;
    }
    #pragma unroll
    for (int nf=0;nf<4;nf++)
      #pragma unroll
      for (int i=0;i<4;i++){
        float e = __expf(sv[nf][i] - mreg[i]);
        sv[nf][i] = e; psum[i] += e;
      }
    #pragma unroll
    for (int i=0;i<4;i++){
      #pragma unroll
      for (int d=1; d<16; d<<=1) psum[i] += __shfl_xor(psum[i], d);
      lsum[i] = lsum[i]*sf[i] + psum[i];
    }
    #pragma unroll
    for (int nf=0;nf<8;nf++)
      #pragma unroll
      for (int i=0;i<4;i++) o[nf][i] *= sf[i];

    // ---- P round-trip (per-wave LDS, no barrier needed) ----
    #pragma unroll
    for (int nf=0;nf<4;nf++)
      #pragma unroll
      for (int i=0;i<4;i++){
        int qi = g*4 + i, kv = nf*16 + lr;
        int idx = qi*64 + (kv ^ ((qi&7)<<3));
        u16 hb = f2b(sv[nf][i]);
        Ph[w][idx] = hb;
        Pl[w][idx] = f2b(sv[nf][i] - b2f(hb));
      }

    // ---- PV (3-pass split) from LDS ----
    #pragma unroll
    for (int kk2=0; kk2<2; kk2++){
      int pidx = lr*64 + ((kk2*32 + g*8) ^ ((lr&7)<<3));
      bf16x8 ph = *(const bf16x8*)(&Ph[w][pidx]);
      bf16x8 pl = *(const bf16x8*)(&Pl[w][pidx]);
      __builtin_amdgcn_s_setprio(1);
      #pragma unroll
      for (int nf=0; nf<8; nf++){
        int row = nf*16 + lr;
        int off = row*64 + ((((kk2<<2)+g) ^ (lr&7))<<3);
        bf16x8 vf = *(const bf16x8*)(&KV[2][off]);
        bf16x8 vg = *(const bf16x8*)(&KV[3][off]);
        o[nf] = __builtin_amdgcn_mfma_f32_16x16x32_bf16(ph, vf, o[nf],0,0,0);
        o[nf] = __builtin_amdgcn_mfma_f32_16x16x32_bf16(ph, vg, o[nf],0,0,0);
        o[nf] = __builtin_amdgcn_mfma_f32_16x16x32_bf16(pl, vf, o[nf],0,0,0);
      }
      __builtin_amdgcn_s_setprio(0);
    }
    __builtin_amdgcn_s_barrier();   // all waves done reading before next stage overwrites
  }

  float inv[4];
  #pragma unroll
  for (int i=0;i<4;i++) inv[i] = 1.0f / lsum[i];
  #pragma unroll
  for (int nf=0;nf<8;nf++)
    #pragma unroll
    for (int i=0;i<4;i++){
      float v = o[nf][i] * inv[i];
      size_t oidx = (size_t)(q0 + g*4 + i)*2048 + h*HD + nf*16 + lr;
      u16 hb = f2b(v);
      oh_[oidx] = hb; ol_[oidx] = f2b(v - b2f(hb));
    }
}

// ---------------- router: fp32 logits, top-2, renorm ----------------
__global__ __launch_bounds__(256) void mx_router(
    const float* __restrict__ h2, const float* __restrict__ gw,
    int* __restrict__ meta, int* __restrict__ tki, float* __restrict__ tkw)
{
  int t = blockIdx.x, tid = threadIdx.x;
  float p[8] = {0,0,0,0,0,0,0,0};
  const float* row = h2 + (size_t)t*H_;
  for (int i = tid; i < H_; i += 256) {
    float x = row[i];
    #pragma unroll
    for (int e=0;e<8;e++) p[e] += x * gw[e*H_ + i];
  }
  #pragma unroll
  for (int e=0;e<8;e++)
    #pragma unroll
    for (int d=32; d; d>>=1) p[e] += __shfl_down(p[e], d);
  __shared__ float red[4][8];
  int w = tid>>6;
  if ((tid&63)==0){
    #pragma unroll
    for (int e=0;e<8;e++) red[w][e] = p[e];
  }
  __syncthreads();
  if (tid==0){
    float lg[8];
    #pragma unroll
    for (int e=0;e<8;e++) lg[e] = red[0][e]+red[1][e]+red[2][e]+red[3][e];
    int e0 = 0;
    for (int e=1;e<8;e++) if (lg[e] > lg[e0]) e0 = e;
    int e1 = (e0==0)?1:0;
    for (int e=0;e<8;e++) if (e!=e0 && lg[e] > lg[e1]) e1 = e;
    float w0 = 1.f/(1.f + __expf(lg[e1]-lg[e0]));
    tki[t*2]=e0; tki[t*2+1]=e1; tkw[t*2]=w0; tkw[t*2+1]=1.f-w0;
    atomicAdd(&meta[e0],1); atomicAdd(&meta[e1],1);
  }
}

// meta: [0..7]=counts [8..15]=poff [16..23]=ptiles [24..31]=cursor; gsh = tile granularity shift
__global__ void mx_scan(int* __restrict__ meta, int* __restrict__ perm, int gsh)
{
  if (threadIdx.x == 0){
    int run = 0;
    for (int e=0;e<8;e++){
      meta[8+e] = run;
      int pt = (meta[e] + (1<<gsh) - 1) >> gsh;
      meta[16+e] = pt;
      run += pt << gsh;
      meta[24+e] = 0;
    }
  }
  for (int i = threadIdx.x; i < PROWS; i += 256) perm[i] = 0;
}

__global__ void mx_scatter(const int* __restrict__ tki, int* __restrict__ meta,
                           int* __restrict__ perm, int* __restrict__ slot)
{
  int t = blockIdx.x*256 + threadIdx.x;
  if (t >= T_) return;
  #pragma unroll
  for (int j=0;j<2;j++){
    int e = tki[t*2+j];
    int s = atomicAdd(&meta[24+e], 1);
    int pos = meta[8+e] + s;
    perm[pos] = t;
    slot[t*2+j] = pos;
  }
}

__global__ void mx_silu(u16* __restrict__ y1, const u16* __restrict__ y3)
{
  size_t base = ((size_t)blockIdx.x*256 + threadIdx.x)*8;
  uint4 a = *(uint4*)(y1+base);
  uint4 b = *(const uint4*)(y3+base);
  u16* ap = (u16*)&a; u16* bp = (u16*)&b;
  uint4 r; u16* rp = (u16*)&r;
  #pragma unroll
  for (int j=0;j<8;j++){
    float gg = b2f(ap[j]), uu = b2f(bp[j]);
    float sg = gg / (1.f + __expf(-gg));
    rp[j] = f2b(sg * uu);
  }
  *(uint4*)(y1+base) = r;
}

__global__ void mx_combine(const float* __restrict__ Y2, const int* __restrict__ slot,
                           const float* __restrict__ tkw, float* __restrict__ out)
{
  int t = blockIdx.x, tid = threadIdx.x;
  int s0 = slot[t*2], s1 = slot[t*2+1];
  float w0 = tkw[t*2], w1 = tkw[t*2+1];
  const float4* r0 = (const float4*)(Y2 + (size_t)s0*H_);
  const float4* r1 = (const float4*)(Y2 + (size_t)s1*H_);
  float4* o4 = (float4*)(out + (size_t)t*H_);
  for (int i = tid; i < 512; i += 256){
    float4 a = r0[i], b = r1[i], c;
    c.x = w0*a.x + w1*b.x; c.y = w0*a.y + w1*b.y;
    c.z = w0*a.z + w1*b.z; c.w = w0*a.w + w1*b.w;
    o4[i] = c;
  }
}

extern "C" void kernel_launch(void* const* d_in, const int* in_sizes, int n_in,
                              void* d_out, int out_size, void* d_ws, size_t ws_size,
                              hipStream_t stream)
{
  (void)in_sizes; (void)n_in; (void)out_size;
  const int*   positions = (const int*)  d_in[0];
  const float* hidden    = (const float*)d_in[1];
  const float* residual  = (const float*)d_in[2];
  const float* ln1       = (const float*)d_in[3];
  const float* ln2       = (const float*)d_in[4];
  const float* wq        = (const float*)d_in[5];
  const float* wk        = (const float*)d_in[6];
  const float* wv        = (const float*)d_in[7];
  const float* wo        = (const float*)d_in[8];
  const float* gatew     = (const float*)d_in[9];
  const float* w1        = (const float*)d_in[10];
  const float* w3        = (const float*)d_in[11];
  const float* w2        = (const float*)d_in[12];
  float* outp = (float*)d_out;                 // [T*H] moe out, then [T*H] residual
  char* ws = (char*)d_ws;

  size_t off = 0;
  auto alloc = [&](size_t n){ size_t o = off; off += (n + 255) & ~(size_t)255; return o; };
  float* cosT = (float*)(ws + alloc((size_t)T_*64*4));
  float* sinT = (float*)(ws + alloc((size_t)T_*64*4));
  size_t res1_off = alloc((size_t)T_*H_*4);
  float* res1 = (float*)(ws + res1_off);
  u16*   h1h  = (u16*)  (ws + alloc((size_t)T_*H_*2));
  u16*   h1l  = (u16*)  (ws + alloc((size_t)T_*H_*2));
  float* qkvF = (float*)(ws + alloc((size_t)T_*3072*4));
  size_t qh_off = alloc((size_t)NH*T_*HD*2);
  u16*   qh   = (u16*)  (ws + qh_off);
  u16*   ql   = (u16*)  (ws + alloc((size_t)NH*T_*HD*2));
  u16*   kh   = (u16*)  (ws + alloc((size_t)NKV*T_*HD*2));
  u16*   kl   = (u16*)  (ws + alloc((size_t)NKV*T_*HD*2));
  u16*   vh   = (u16*)  (ws + alloc((size_t)NKV*T_*HD*2));
  u16*   vl   = (u16*)  (ws + alloc((size_t)NKV*T_*HD*2));
  u16*   aoh  = (u16*)  (ws + alloc((size_t)T_*2048*2));
  u16*   aol  = (u16*)  (ws + alloc((size_t)T_*2048*2));
  float* oF   = (float*)(ws + alloc((size_t)T_*H_*4));
  float* h2f  = (float*)(ws + alloc((size_t)T_*H_*4));
  u16*   h2b  = (u16*)  (ws + alloc((size_t)T_*H_*2));
  int*   meta = (int*)  (ws + alloc(32*4));
  int*   tki  = (int*)  (ws + alloc((size_t)T_*2*4));
  float* tkw  = (float*)(ws + alloc((size_t)T_*2*4));
  int*   slot = (int*)  (ws + alloc((size_t)T_*2*4));
  int*   perm = (int*)  (ws + alloc((size_t)PROWS*4));
  u16*   Y1   = (u16*)  (ws + alloc((size_t)PROWS*II_*2));
  // Y3 aliases res1..qkvF (dead before MoE GEMMs); Y2 aliases qh..oF (dead before w2 GEMM)
  u16*   Y3   = (u16*)  (ws + res1_off);
  float* Y2   = (float*)(ws + qh_off);
  // bf16 weight copies — allocated last, gated on ws_size
  u16* w1b = (u16*)(ws + alloc((size_t)NE*II_*H_*2));
  u16* w3b = (u16*)(ws + alloc((size_t)NE*II_*H_*2));
  u16* w2b = (u16*)(ws + alloc((size_t)NE*H_*II_*2));
  u16* qwh = (u16*)(ws + alloc((size_t)3072*H_*2));   // wq|wk|wv rows concat, split-hi
  u16* qwl = (u16*)(ws + alloc((size_t)3072*H_*2));
  u16* woh = (u16*)(ws + alloc((size_t)H_*H_*2));
  u16* wol = (u16*)(ws + alloc((size_t)H_*H_*2));
  bool big = ws_size >= off;

  if (big){
    // 0. weight conversions
    int n8 = NE*II_*H_/8;
    mx_cvt<<<2048, 256, 0, stream>>>(w1, w1b, n8);
    mx_cvt<<<2048, 256, 0, stream>>>(w3, w3b, n8);
    mx_cvt<<<2048, 256, 0, stream>>>(w2, w2b, n8);
    mx_cvt_split<<<512, 256, 0, stream>>>(wq, qwh,                qwl,                2048*2048/8);
    mx_cvt_split<<<512, 256, 0, stream>>>(wk, qwh + 2048*2048,    qwl + 2048*2048,    512*2048/8);
    mx_cvt_split<<<512, 256, 0, stream>>>(wv, qwh + 2560*2048,    qwl + 2560*2048,    512*2048/8);
    mx_cvt_split<<<512, 256, 0, stream>>>(wo, woh,                wol,                2048*2048/8);
  }
  // 1. RoPE tables + fused add+norm1
  mx_rope_table<<<512, 256, 0, stream>>>(positions, cosT, sinT);
  mx_addnorm<<<T_, 256, 0, stream>>>(hidden, residual, ln1, res1, h1h, h1l,
                                     nullptr, nullptr, nullptr);
  // 2. QKV projection (3-pass split)
  if (big){
    mx_gemm3g<16,24><<<384, 256, 0, stream>>>(h1h, h1l, qwh, qwl, qkvF, 3072, H_);
  } else {
    mx_gemm3<16,16><<<256, 256, 0, stream>>>(h1h, h1l, H_, wq, qkvF,        3072, H_);
    mx_gemm3<16, 4><<< 64, 256, 0, stream>>>(h1h, h1l, H_, wk, qkvF + 2048, 3072, H_);
    mx_gemm3<16, 4><<< 64, 256, 0, stream>>>(h1h, h1l, H_, wv, qkvF + 2560, 3072, H_);
  }
  // 3. RoPE apply + V transpose
  mx_rope_apply<<<dim3(T_/4, NH+NKV), 256, 0, stream>>>(qkvF, cosT, sinT, qh, ql, kh, kl);
  mx_transpose_v<<<dim3(NKV, T_/64), 256, 0, stream>>>(qkvF, vh, vl);
  // 4. attention
  mx_attn<<<dim3(T_/64, NH), 256, 0, stream>>>(qh, ql, kh, kl, vh, vl, aoh, aol);
  // 5. o_proj (3-pass split)
  if (big){
    mx_gemm3g<16,16><<<256, 256, 0, stream>>>(aoh, aol, woh, wol, oF, 2048, 2048);
  } else {
    mx_gemm3<16,16><<<256, 256, 0, stream>>>(aoh, aol, 2048, wo, oF, H_, 2048);
  }
  // 6. add + norm2 (residual output + h2 fp32 + h2 bf16); zero expert counts
  mx_addnorm<<<T_, 256, 0, stream>>>(oF, res1, ln2, outp + (size_t)T_*H_,
                                     nullptr, nullptr, h2f, h2b, meta);
  // 7. router + routing metadata
  mx_router<<<T_, 256, 0, stream>>>(h2f, gatew, meta, tki, tkw);
  mx_scan<<<1, 256, 0, stream>>>(meta, perm, big ? 7 : 8);
  mx_scatter<<<T_/256, 256, 0, stream>>>(tki, meta, perm, slot);
  // 8. MoE expert GEMMs
  if (big){
    mx_moe_w13<32><<<4096, 256, 0, stream>>>(h2b, w1b, w3b, Y1, perm, meta);
    mx_moe_w2k<16><<<2048, 256, 0, stream>>>(Y1, w2b, Y2, meta);
  } else {
    mx_moe10<1,1,64,32><<<4096, 512, 0, stream>>>(h2b, H_, w1, w3, (long long)II_*H_,
                                                  Y1, Y3, II_, H_, perm, meta);
    mx_silu<<<(PROWS*II_/8)/256, 256, 0, stream>>>(Y1, Y3);
    mx_moe10<0,0,16,16><<<1024, 512, 0, stream>>>(Y1, II_, w2, w2, (long long)H_*II_,
                                                  Y2, Y2, H_, II_, perm, meta);
  }
  // 9. combine weighted expert outputs -> out
  mx_combine<<<T_, 256, 0, stream>>>(Y2, slot, tkw, outp);
}

// Round 11
// 1026.035 us; speedup vs baseline: 1.2535x; 1.0558x over previous
//
#include <hip/hip_runtime.h>
#include <hip/hip_bf16.h>
#include <math.h>

// Mixtral decoder layer, MI355X. T=2048 H=2048 NH=16 NKV=4 HD=128 I=4096 E=8 TOPK=2.
// Pre-router path (QKV, attn, o_proj): 3-pass bf16-split MFMA (~fp32 accurate) so the
// router top-k matches the fp32 reference; MoE expert path is plain bf16.
// R11: attn processes 2 heads/block (8 waves, shared K/V stage), dbuf 160KB LDS with
// counted vmcnt(8) — one staging serves 2x the MFMA, no mid-loop drain.

#define T_  2048
#define H_  2048
#define NH  16
#define NKV 4
#define HD  128
#define II_ 4096
#define NE  8
#define EPS 1e-5f
#define PROWS 6144   // padded permuted rows

typedef __bf16 bf16x8 __attribute__((ext_vector_type(8)));
typedef float  f32x4  __attribute__((ext_vector_type(4)));
typedef unsigned short u16;

__device__ __forceinline__ u16 f2b(float f){ __bf16 b = (__bf16)f; return __builtin_bit_cast(u16, b); }
__device__ __forceinline__ float b2f(u16 u){ return (float)__builtin_bit_cast(__bf16, u); }

__device__ __forceinline__ void gll16(const void* g, void* l){
  __builtin_amdgcn_global_load_lds(
      (const __attribute__((address_space(1))) unsigned int*)g,
      (__attribute__((address_space(3))) unsigned int*)l, 16, 0, 0);
}

__device__ __forceinline__ bf16x8 cvt8(f32x4 a, f32x4 b){
  uint4 u;
  u.x = (unsigned)f2b(a[0]) | ((unsigned)f2b(a[1])<<16);
  u.y = (unsigned)f2b(a[2]) | ((unsigned)f2b(a[3])<<16);
  u.z = (unsigned)f2b(b[0]) | ((unsigned)f2b(b[1])<<16);
  u.w = (unsigned)f2b(b[2]) | ((unsigned)f2b(b[3])<<16);
  return __builtin_bit_cast(bf16x8, u);
}

// ---------------- fp32 -> packed bf16 streaming conversion ----------------
__global__ __launch_bounds__(256) void mx_cvt(const float* __restrict__ s,
                                              u16* __restrict__ d, int n8)
{
  int i = blockIdx.x*256 + threadIdx.x;
  int stride = gridDim.x*256;
  for (; i < n8; i += stride){
    const f32x4* p = (const f32x4*)s + 2*(size_t)i;
    f32x4 a = p[0], b = p[1];
    uint4 u;
    u.x = (unsigned)f2b(a[0]) | ((unsigned)f2b(a[1])<<16);
    u.y = (unsigned)f2b(a[2]) | ((unsigned)f2b(a[3])<<16);
    u.z = (unsigned)f2b(b[0]) | ((unsigned)f2b(b[1])<<16);
    u.w = (unsigned)f2b(b[2]) | ((unsigned)f2b(b[3])<<16);
    ((uint4*)d)[i] = u;
  }
}

// ---------------- fp32 -> split (hi, lo) bf16 conversion ----------------
__global__ __launch_bounds__(256) void mx_cvt_split(const float* __restrict__ s,
                                                    u16* __restrict__ hi,
                                                    u16* __restrict__ lo, int n8)
{
  int i = blockIdx.x*256 + threadIdx.x;
  int stride = gridDim.x*256;
  for (; i < n8; i += stride){
    const f32x4* p = (const f32x4*)s + 2*(size_t)i;
    f32x4 a = p[0], b = p[1];
    uint4 uh, ul;
    u16 h0,h1,h2,h3;
    h0=f2b(a[0]); h1=f2b(a[1]); h2=f2b(a[2]); h3=f2b(a[3]);
    uh.x = (unsigned)h0 | ((unsigned)h1<<16);
    uh.y = (unsigned)h2 | ((unsigned)h3<<16);
    ul.x = (unsigned)f2b(a[0]-b2f(h0)) | ((unsigned)f2b(a[1]-b2f(h1))<<16);
    ul.y = (unsigned)f2b(a[2]-b2f(h2)) | ((unsigned)f2b(a[3]-b2f(h3))<<16);
    h0=f2b(b[0]); h1=f2b(b[1]); h2=f2b(b[2]); h3=f2b(b[3]);
    uh.z = (unsigned)h0 | ((unsigned)h1<<16);
    uh.w = (unsigned)h2 | ((unsigned)h3<<16);
    ul.z = (unsigned)f2b(b[0]-b2f(h0)) | ((unsigned)f2b(b[1]-b2f(h1))<<16);
    ul.w = (unsigned)f2b(b[2]-b2f(h2)) | ((unsigned)f2b(b[3]-b2f(h3))<<16);
    ((uint4*)hi)[i] = uh;
    ((uint4*)lo)[i] = ul;
  }
}

// ---------------- RoPE cos/sin table (double-precision inv_freq) ----------------
__global__ void mx_rope_table(const int* __restrict__ pos, float* __restrict__ cosT,
                              float* __restrict__ sinT)
{
  int i = blockIdx.x*256 + threadIdx.x;            // T*64
  int t = i >> 6, d = i & 63;
  float inv = (float)exp(-((double)d/64.0) * 9.210340371976184); // 10000^{-d/64}
  float f = (float)pos[t] * inv;
  cosT[i] = cosf(f); sinT[i] = sinf(f);
}

// ---------------- fused add + RMSNorm (writes several output forms) ----------------
__global__ __launch_bounds__(256) void mx_addnorm(
    const float* __restrict__ a, const float* __restrict__ b,
    const float* __restrict__ gam, float* __restrict__ res_out,
    u16* __restrict__ hi, u16* __restrict__ lo,
    float* __restrict__ hf, u16* __restrict__ hbf, int* __restrict__ mz)
{
  int t = blockIdx.x, tid = threadIdx.x;
  if (mz && t == 0 && tid < 8) mz[tid] = 0;
  const float4* A4 = (const float4*)a + (size_t)t*512;
  const float4* B4 = (const float4*)b + (size_t)t*512;
  float4 va = A4[tid], vb = B4[tid];
  float4 x0; x0.x=va.x+vb.x; x0.y=va.y+vb.y; x0.z=va.z+vb.z; x0.w=va.w+vb.w;
  va = A4[tid+256]; vb = B4[tid+256];
  float4 x1; x1.x=va.x+vb.x; x1.y=va.y+vb.y; x1.z=va.z+vb.z; x1.w=va.w+vb.w;
  float ss = x0.x*x0.x + x0.y*x0.y + x0.z*x0.z + x0.w*x0.w
           + x1.x*x1.x + x1.y*x1.y + x1.z*x1.z + x1.w*x1.w;
  #pragma unroll
  for (int d=32; d; d>>=1) ss += __shfl_down(ss, d);
  __shared__ float red[4];
  if ((tid&63)==0) red[tid>>6] = ss;
  __syncthreads();
  ss = red[0]+red[1]+red[2]+red[3];
  float scale = rsqrtf(ss * (1.f/2048.f) + EPS);
  float4* R4 = (float4*)res_out + (size_t)t*512;
  R4[tid] = x0; R4[tid+256] = x1;
  const float4* G4p = (const float4*)gam;
  float4 g0 = G4p[tid], g1 = G4p[tid+256];
  float4 y0; y0.x=x0.x*scale*g0.x; y0.y=x0.y*scale*g0.y; y0.z=x0.z*scale*g0.z; y0.w=x0.w*scale*g0.w;
  float4 y1; y1.x=x1.x*scale*g1.x; y1.y=x1.y*scale*g1.y; y1.z=x1.z*scale*g1.z; y1.w=x1.w*scale*g1.w;
  if (hf){ float4* H4 = (float4*)hf + (size_t)t*512; H4[tid]=y0; H4[tid+256]=y1; }
  if (hi){
    ushort4 uh, ul;
    uh.x=f2b(y0.x); ul.x=f2b(y0.x-b2f(uh.x));
    uh.y=f2b(y0.y); ul.y=f2b(y0.y-b2f(uh.y));
    uh.z=f2b(y0.z); ul.z=f2b(y0.z-b2f(uh.z));
    uh.w=f2b(y0.w); ul.w=f2b(y0.w-b2f(uh.w));
    ((ushort4*)hi)[(size_t)t*512 + tid] = uh; ((ushort4*)lo)[(size_t)t*512 + tid] = ul;
    uh.x=f2b(y1.x); ul.x=f2b(y1.x-b2f(uh.x));
    uh.y=f2b(y1.y); ul.y=f2b(y1.y-b2f(uh.y));
    uh.z=f2b(y1.z); ul.z=f2b(y1.z-b2f(uh.z));
    uh.w=f2b(y1.w); ul.w=f2b(y1.w-b2f(uh.w));
    ((ushort4*)hi)[(size_t)t*512 + tid+256] = uh; ((ushort4*)lo)[(size_t)t*512 + tid+256] = ul;
  }
  if (hbf){
    ushort4 u0; u0.x=f2b(y0.x); u0.y=f2b(y0.y); u0.z=f2b(y0.z); u0.w=f2b(y0.w);
    ushort4 u1; u1.x=f2b(y1.x); u1.y=f2b(y1.y); u1.z=f2b(y1.z); u1.w=f2b(y1.w);
    ((ushort4*)hbf)[(size_t)t*512 + tid] = u0; ((ushort4*)hbf)[(size_t)t*512 + tid+256] = u1;
  }
}

// ------- 3-pass split GEMM, gll16 m97 skeleton: C = A(hi,lo) x B(hi,lo)^T, fp32 out -------
template<int NX, int NY>
__global__ __launch_bounds__(256,2) void mx_gemm3g(
    const u16* __restrict__ Ah, const u16* __restrict__ Al,
    const u16* __restrict__ Bh, const u16* __restrict__ Bl,
    float* __restrict__ C, int ldc, int K)
{
  __shared__ u16 AhS[128*64], AlS[128*64], BhS[128*64], BlS[128*64];
  int bid = blockIdx.x;
  int xcd = bid & 7, j = bid >> 3;
  int x = j % NX, p = j / NX;
  int y = xcd + 8*p;
  int m0 = x*128, n0 = y*128;
  int tid = threadIdx.x;
  int w = tid>>6, lane = tid&63, wr = w>>1, wc = w&1, g = lane>>4, lr = lane&15;
  f32x4 acc[4][4];
  #pragma unroll
  for (int fm=0;fm<4;fm++)
    #pragma unroll
    for (int fn=0;fn<4;fn++) acc[fm][fn] = (f32x4){0.f,0.f,0.f,0.f};

  for (int k0 = 0; k0 < K; k0 += 64) {
    #pragma unroll
    for (int i=0;i<4;i++){
      int c = i*256 + tid, r = c>>3, ch = c&7;
      int sw = ((ch ^ (r&7))<<3);
      int db = (i*256 + w*64)<<3;
      gll16(Ah + (size_t)(m0+r)*K + k0 + sw, &AhS[db]);
      gll16(Al + (size_t)(m0+r)*K + k0 + sw, &AlS[db]);
      gll16(Bh + (size_t)(n0+r)*K + k0 + sw, &BhS[db]);
      gll16(Bl + (size_t)(n0+r)*K + k0 + sw, &BlS[db]);
    }
    __syncthreads();
    #pragma unroll
    for (int kk=0;kk<2;kk++){
      bf16x8 ah[4], al[4], bh[4], bl[4];
      #pragma unroll
      for (int fm=0;fm<4;fm++){
        int r = wr*64 + fm*16 + lr;
        int ch = ((kk<<2)+g) ^ (r&7);
        ah[fm] = *(const bf16x8*)(&AhS[(r<<6)+(ch<<3)]);
        al[fm] = *(const bf16x8*)(&AlS[(r<<6)+(ch<<3)]);
      }
      #pragma unroll
      for (int fn=0;fn<4;fn++){
        int r = wc*64 + fn*16 + lr;
        int ch = ((kk<<2)+g) ^ (r&7);
        bh[fn] = *(const bf16x8*)(&BhS[(r<<6)+(ch<<3)]);
        bl[fn] = *(const bf16x8*)(&BlS[(r<<6)+(ch<<3)]);
      }
      __builtin_amdgcn_s_setprio(1);
      #pragma unroll
      for (int fm=0;fm<4;fm++)
        #pragma unroll
        for (int fn=0;fn<4;fn++){
          acc[fm][fn] = __builtin_amdgcn_mfma_f32_16x16x32_bf16(ah[fm], bh[fn], acc[fm][fn],0,0,0);
          acc[fm][fn] = __builtin_amdgcn_mfma_f32_16x16x32_bf16(ah[fm], bl[fn], acc[fm][fn],0,0,0);
          acc[fm][fn] = __builtin_amdgcn_mfma_f32_16x16x32_bf16(al[fm], bh[fn], acc[fm][fn],0,0,0);
        }
      __builtin_amdgcn_s_setprio(0);
    }
    __syncthreads();
  }
  #pragma unroll
  for (int fm=0;fm<4;fm++)
    #pragma unroll
    for (int fn=0;fn<4;fn++)
      #pragma unroll
      for (int i=0;i<4;i++){
        size_t rg = (size_t)(m0 + wr*64 + fm*16 + g*4 + i);
        int cg = n0 + wc*64 + fn*16 + lr;
        C[rg*ldc + cg] = acc[fm][fn][i];
      }
}

// ------------- 3-pass split-bf16 GEMM (fallback, fp32 B in-loop) -------------
template<int NX, int NY>
__global__ __launch_bounds__(256) void mx_gemm3(
    const u16* __restrict__ Ah, const u16* __restrict__ Al, int lda,
    const float* __restrict__ B,
    float* __restrict__ C, int ldc, int K)
{
  const int LDT = 72;
  __shared__ u16 Ash[128*LDT], Asl[128*LDT], Bsh[128*LDT], Bsl[128*LDT];
  int bid = blockIdx.x, x, y;
  if constexpr ((NY & 7) == 0) {
    int xcd = bid & 7, j = bid >> 3;
    x = j % NX; int p = j / NX;
    y = xcd + 8*p;
  } else { x = bid % NX; y = bid / NX; }
  int m0 = x*128, n0 = y*128;
  int tid = threadIdx.x;
  int w = tid>>6, lane = tid&63, wr = w>>1, wc = w&1, g = lane>>4, lr = lane&15;
  f32x4 acc[4][4];
  #pragma unroll
  for (int fm=0;fm<4;fm++)
    #pragma unroll
    for (int fn=0;fn<4;fn++) acc[fm][fn] = (f32x4){0.f,0.f,0.f,0.f};
  for (int k0 = 0; k0 < K; k0 += 64) {
    #pragma unroll
    for (int i=0;i<4;i++){
      int c = i*256 + tid, r = c>>3, ch = c&7;
      *(uint4*)(&Ash[r*LDT + ch*8]) = *(const uint4*)(Ah + (size_t)(m0+r)*lda + k0 + ch*8);
      *(uint4*)(&Asl[r*LDT + ch*8]) = *(const uint4*)(Al + (size_t)(m0+r)*lda + k0 + ch*8);
    }
    #pragma unroll
    for (int i=0;i<8;i++){
      int f = i*256 + tid, r = f>>4, c4 = f&15;
      float4 v = *(const float4*)(B + (size_t)(n0+r)*K + k0 + c4*4);
      ushort4 hv, lv;
      hv.x=f2b(v.x); lv.x=f2b(v.x-b2f(hv.x));
      hv.y=f2b(v.y); lv.y=f2b(v.y-b2f(hv.y));
      hv.z=f2b(v.z); lv.z=f2b(v.z-b2f(hv.z));
      hv.w=f2b(v.w); lv.w=f2b(v.w-b2f(hv.w));
      *(ushort4*)(&Bsh[r*LDT + c4*4]) = hv;
      *(ushort4*)(&Bsl[r*LDT + c4*4]) = lv;
    }
    __syncthreads();
    #pragma unroll
    for (int kk=0;kk<2;kk++){
      bf16x8 ah[4], al[4], bh[4], bl[4];
      #pragma unroll
      for (int fm=0;fm<4;fm++){
        int r = wr*64 + fm*16 + lr;
        ah[fm] = *(const bf16x8*)(&Ash[r*LDT + kk*32 + g*8]);
        al[fm] = *(const bf16x8*)(&Asl[r*LDT + kk*32 + g*8]);
      }
      #pragma unroll
      for (int fn=0;fn<4;fn++){
        int r = wc*64 + fn*16 + lr;
        bh[fn] = *(const bf16x8*)(&Bsh[r*LDT + kk*32 + g*8]);
        bl[fn] = *(const bf16x8*)(&Bsl[r*LDT + kk*32 + g*8]);
      }
      __builtin_amdgcn_s_setprio(1);
      #pragma unroll
      for (int fm=0;fm<4;fm++)
        #pragma unroll
        for (int fn=0;fn<4;fn++){
          acc[fm][fn] = __builtin_amdgcn_mfma_f32_16x16x32_bf16(ah[fm], bh[fn], acc[fm][fn],0,0,0);
          acc[fm][fn] = __builtin_amdgcn_mfma_f32_16x16x32_bf16(ah[fm], bl[fn], acc[fm][fn],0,0,0);
          acc[fm][fn] = __builtin_amdgcn_mfma_f32_16x16x32_bf16(al[fm], bh[fn], acc[fm][fn],0,0,0);
        }
      __builtin_amdgcn_s_setprio(0);
    }
    __syncthreads();
  }
  #pragma unroll
  for (int fm=0;fm<4;fm++)
    #pragma unroll
    for (int fn=0;fn<4;fn++)
      #pragma unroll
      for (int i=0;i<4;i++){
        size_t rg = (size_t)(m0 + wr*64 + fm*16 + g*4 + i);
        int cg = n0 + wc*64 + fn*16 + lr;
        C[rg*ldc + cg] = acc[fm][fn][i];
      }
}

// ------------- MoE w1+w3 fused GEMM + silu epilogue (all-bf16, m97-style) -------------
template<int NY>
__global__ __launch_bounds__(256,2) void mx_moe_w13(
    const u16* __restrict__ A,
    const u16* __restrict__ B1, const u16* __restrict__ B3,
    u16* __restrict__ Y,
    const int* __restrict__ row_map, const int* __restrict__ meta)
{
  __shared__ u16 As[128*64], B1s[128*64], B3s[128*64];
  int bid = blockIdx.x;
  int xcd = bid & 7, j = bid >> 3;
  int x = j & 15, p = j >> 4;
  int panel = xcd + 8*p;                 // < NE*NY
  int e = panel / NY, y = panel % NY;
  if (x >= meta[16+e]) return;
  int rowbase = meta[8+e] + (x<<7);
  const u16* B1p = B1 + ((size_t)e*II_ + y*128)*H_;
  const u16* B3p = B3 + ((size_t)e*II_ + y*128)*H_;
  int tid = threadIdx.x;
  int w = tid>>6, lane = tid&63, wr = w>>1, wc = w&1, g = lane>>4, lr = lane&15;

  f32x4 acc1[4][4], acc3[4][4];
  #pragma unroll
  for (int fm=0;fm<4;fm++)
    #pragma unroll
    for (int fn=0;fn<4;fn++){ acc1[fm][fn]=(f32x4){0,0,0,0}; acc3[fm][fn]=(f32x4){0,0,0,0}; }

  for (int k0 = 0; k0 < H_; k0 += 64) {
    #pragma unroll
    for (int i=0;i<4;i++){
      int c = i*256 + tid, r = c>>3, ch = c&7;
      int sw = (ch ^ (r&7))<<3;
      int db = (i*256 + w*64)<<3;
      int grow = row_map[rowbase + r];
      gll16(A   + (size_t)grow*H_ + k0 + sw, &As[db]);
      gll16(B1p + (size_t)r*H_    + k0 + sw, &B1s[db]);
      gll16(B3p + (size_t)r*H_    + k0 + sw, &B3s[db]);
    }
    __syncthreads();
    #pragma unroll
    for (int kk=0;kk<2;kk++){
      bf16x8 af[4], b1f[4], b3f[4];
      #pragma unroll
      for (int fm=0;fm<4;fm++){
        int r = wr*64 + fm*16 + lr;
        int ch = ((kk<<2)+g) ^ (r&7);
        af[fm] = *(const bf16x8*)(&As[(r<<6)+(ch<<3)]);
      }
      #pragma unroll
      for (int fn=0;fn<4;fn++){
        int r = wc*64 + fn*16 + lr;
        int ch = ((kk<<2)+g) ^ (r&7);
        b1f[fn] = *(const bf16x8*)(&B1s[(r<<6)+(ch<<3)]);
        b3f[fn] = *(const bf16x8*)(&B3s[(r<<6)+(ch<<3)]);
      }
      __builtin_amdgcn_s_setprio(1);
      #pragma unroll
      for (int fm=0;fm<4;fm++)
        #pragma unroll
        for (int fn=0;fn<4;fn++){
          acc1[fm][fn] = __builtin_amdgcn_mfma_f32_16x16x32_bf16(af[fm], b1f[fn], acc1[fm][fn],0,0,0);
          acc3[fm][fn] = __builtin_amdgcn_mfma_f32_16x16x32_bf16(af[fm], b3f[fn], acc3[fm][fn],0,0,0);
        }
      __builtin_amdgcn_s_setprio(0);
    }
    __syncthreads();
  }
  int n0 = y*128 + wc*64;
  #pragma unroll
  for (int fm=0;fm<4;fm++)
    #pragma unroll
    for (int fn=0;fn<4;fn++)
      #pragma unroll
      for (int i=0;i<4;i++){
        size_t rg = (size_t)(rowbase + wr*64 + fm*16 + g*4 + i);
        int cg = n0 + fn*16 + lr;
        float gg = acc1[fm][fn][i], uu = acc3[fm][fn][i];
        float sg = gg / (1.f + __expf(-gg));
        Y[rg*II_ + cg] = f2b(sg * uu);
      }
}

// ------------- MoE w2 GEMM (all-bf16, m97-style): Y2 = Y . w2^T -------------
template<int NY>
__global__ __launch_bounds__(256,2) void mx_moe_w2k(
    const u16* __restrict__ A,       // Y bf16 [PROWS][II_]
    const u16* __restrict__ B,       // w2b bf16 [E][H_][II_]
    float* __restrict__ C,           // Y2 fp32 [PROWS][H_]
    const int* __restrict__ meta)
{
  __shared__ u16 As[128*64], Bs[128*64];
  int bid = blockIdx.x;
  int xcd = bid & 7, j = bid >> 3;
  int x = j & 15, p = j >> 4;
  int panel = xcd + 8*p;                 // < NE*NY
  int e = panel / NY, y = panel % NY;
  if (x >= meta[16+e]) return;
  int rowbase = meta[8+e] + (x<<7);
  const u16* Bp = B + ((size_t)e*H_ + y*128)*II_;
  int tid = threadIdx.x;
  int w = tid>>6, lane = tid&63, wr = w>>1, wc = w&1, g = lane>>4, lr = lane&15;

  f32x4 acc[4][4];
  #pragma unroll
  for (int fm=0;fm<4;fm++)
    #pragma unroll
    for (int fn=0;fn<4;fn++) acc[fm][fn] = (f32x4){0,0,0,0};

  for (int k0 = 0; k0 < II_; k0 += 64) {
    #pragma unroll
    for (int i=0;i<4;i++){
      int c = i*256 + tid, r = c>>3, ch = c&7;
      int sw = (ch ^ (r&7))<<3;
      int db = (i*256 + w*64)<<3;
      gll16(A  + (size_t)(rowbase + r)*II_ + k0 + sw, &As[db]);
      gll16(Bp + (size_t)r*II_             + k0 + sw, &Bs[db]);
    }
    __syncthreads();
    #pragma unroll
    for (int kk=0;kk<2;kk++){
      bf16x8 af[4], bf[4];
      #pragma unroll
      for (int fm=0;fm<4;fm++){
        int r = wr*64 + fm*16 + lr;
        int ch = ((kk<<2)+g) ^ (r&7);
        af[fm] = *(const bf16x8*)(&As[(r<<6)+(ch<<3)]);
      }
      #pragma unroll
      for (int fn=0;fn<4;fn++){
        int r = wc*64 + fn*16 + lr;
        int ch = ((kk<<2)+g) ^ (r&7);
        bf[fn] = *(const bf16x8*)(&Bs[(r<<6)+(ch<<3)]);
      }
      __builtin_amdgcn_s_setprio(1);
      #pragma unroll
      for (int fm=0;fm<4;fm++)
        #pragma unroll
        for (int fn=0;fn<4;fn++)
          acc[fm][fn] = __builtin_amdgcn_mfma_f32_16x16x32_bf16(af[fm], bf[fn], acc[fm][fn],0,0,0);
      __builtin_amdgcn_s_setprio(0);
    }
    __syncthreads();
  }
  int n0 = y*128 + wc*64;
  #pragma unroll
  for (int fm=0;fm<4;fm++)
    #pragma unroll
    for (int fn=0;fn<4;fn++)
      #pragma unroll
      for (int i=0;i<4;i++){
        size_t rg = (size_t)(rowbase + wr*64 + fm*16 + g*4 + i);
        int cg = n0 + fn*16 + lr;
        C[rg*H_ + cg] = acc[fm][fn][i];
      }
}

// ---------------- RoPE apply: qkv fp32 -> split-bf16 Q [h][t][d], K [kv][t][d] ----------------
__global__ __launch_bounds__(256) void mx_rope_apply(const float* __restrict__ qkv,
    const float* __restrict__ cosT, const float* __restrict__ sinT,
    u16* __restrict__ qh, u16* __restrict__ ql, u16* __restrict__ kh, u16* __restrict__ kl)
{
  int t = blockIdx.x*4 + (threadIdx.x>>6);
  int hh = blockIdx.y, d = threadIdx.x & 63;
  const float* row = qkv + (size_t)t*3072;
  float c = cosT[t*64+d], s = sinT[t*64+d];
  float x1, x2; size_t base; u16 *oh, *ol;
  if (hh < NH){ x1 = row[hh*HD+d]; x2 = row[hh*HD+d+64];
     base = ((size_t)hh*T_ + t)*HD; oh = qh; ol = ql; }
  else { int kvh = hh-NH; x1 = row[2048 + kvh*HD + d]; x2 = row[2048 + kvh*HD + d + 64];
     base = ((size_t)kvh*T_ + t)*HD; oh = kh; ol = kl; }
  float o1 = x1*c - x2*s, o2 = x2*c + x1*s;
  u16 a = f2b(o1); oh[base+d]    = a; ol[base+d]    = f2b(o1 - b2f(a));
  u16 b = f2b(o2); oh[base+d+64] = b; ol[base+d+64] = f2b(o2 - b2f(b));
}

// ---------------- V transpose: qkv fp32 -> split-bf16 V^T [kv][d][t] ----------------
__global__ void mx_transpose_v(const float* __restrict__ qkv,
                               u16* __restrict__ vh, u16* __restrict__ vl)
{
  __shared__ float tile[64][132];
  int kv = blockIdx.x, t0 = blockIdx.y*64, tid = threadIdx.x;
  #pragma unroll
  for (int it=0; it<32; ++it){
    int idx = it*256 + tid; int r = idx>>7, d = idx&127;
    tile[r][d] = qkv[(size_t)(t0+r)*3072 + 2560 + kv*HD + d];
  }
  __syncthreads();
  #pragma unroll
  for (int it=0; it<32; ++it){
    int idx = it*256 + tid; int d = idx>>6, j = idx&63;
    float x = tile[j][d];
    u16 a = f2b(x);
    size_t o = ((size_t)kv*HD + d)*T_ + t0 + j;
    vh[o] = a; vl[o] = f2b(x - b2f(a));
  }
}

// ---------------- flash attention, causal GQA, 3-pass split-bf16 ----------------
// 2 heads per block (same kvh): waves 0-3 -> head A, waves 4-7 -> head B; one shared
// K/V staging serves both heads. Double-buffered 160KB LDS, counted vmcnt(8).
__global__ __launch_bounds__(512) void mx_attn(
  const u16* __restrict__ qh_, const u16* __restrict__ ql_,
  const u16* __restrict__ kh_, const u16* __restrict__ kl_,
  const u16* __restrict__ vh_, const u16* __restrict__ vl_,
  u16* __restrict__ oh_, u16* __restrict__ ol_)
{
  int pair = blockIdx.y;                    // 0..7 -> heads (2p, 2p+1)
  int kvh = pair >> 1;
  int qt = (pair & 4) ? (31 - (int)blockIdx.x) : (int)blockIdx.x;
  int tid = threadIdx.x, w = tid>>6, lane = tid&63, g = lane>>4, lr = lane&15;
  int head = pair*2 + (w>>2);
  int q0 = qt*64 + (w&3)*16;
  __shared__ u16 KV[2][4][8192];            // [buf][Kh,Kl,Vh,Vl] 128 KB
  __shared__ u16 Ph[8][1024], Pl[8][1024];  // 32 KB (per-wave)

  bf16x8 qfh[4], qfl[4];
  const u16* qrh = qh_ + ((size_t)head*T_ + q0 + lr)*HD;
  const u16* qrl = ql_ + ((size_t)head*T_ + q0 + lr)*HD;
  #pragma unroll
  for (int kk=0;kk<4;kk++){
    qfh[kk] = *(const bf16x8*)(qrh + kk*32 + g*8);
    qfl[kk] = *(const bf16x8*)(qrl + kk*32 + g*8);
  }
  f32x4 o[8];
  #pragma unroll
  for (int nf=0;nf<8;nf++) o[nf] = (f32x4){0.f,0.f,0.f,0.f};
  float mreg[4] = {-3e38f,-3e38f,-3e38f,-3e38f}, lsum[4] = {0.f,0.f,0.f,0.f};

  const u16* kbase = kh_ + (size_t)kvh*T_*HD;
  const u16* lbase = kl_ + (size_t)kvh*T_*HD;
  const u16* vbase = vh_ + (size_t)kvh*HD*T_;
  const u16* wbase = vl_ + (size_t)kvh*HD*T_;

  auto stage = [&](int buf, int kvb){
    #pragma unroll
    for (int i=0;i<2;i++){
      int cb = i*512 + w*64;                // wave-uniform chunk base (0..1023)
      int c  = cb + lane;
      int kr = c>>4, kc = ((c&15) ^ (kr&7))<<3;
      gll16(kbase + (size_t)(kvb+kr)*HD + kc, &KV[buf][0][cb*8]);
      gll16(lbase + (size_t)(kvb+kr)*HD + kc, &KV[buf][1][cb*8]);
      int vr = c>>3, vc = ((c&7) ^ (vr&7))<<3;
      gll16(vbase + (size_t)vr*T_ + kvb + vc, &KV[buf][2][cb*8]);
      gll16(wbase + (size_t)vr*T_ + kvb + vc, &KV[buf][3][cb*8]);
    }
  };

  stage(0, 0);      // prologue: 8 loads/thread in flight

  for (int kt = 0; kt <= qt; ++kt) {
    int cur = kt & 1;
    int kvb = kt*64;
    if (kt < qt) {
      stage(cur^1, kvb+64);
      asm volatile("s_waitcnt vmcnt(8)" ::: "memory");   // cur tile landed, next in flight
    } else {
      asm volatile("s_waitcnt vmcnt(0)" ::: "memory");
    }
    __builtin_amdgcn_s_barrier();

    // ---- QK^T (3-pass split) from LDS ----
    f32x4 s[4];
    #pragma unroll
    for (int nf=0;nf<4;nf++) s[nf] = (f32x4){0.f,0.f,0.f,0.f};
    __builtin_amdgcn_s_setprio(1);
    #pragma unroll
    for (int nf=0; nf<4; nf++){
      int row = nf*16 + lr;
      #pragma unroll
      for (int kk=0;kk<4;kk++){
        int off = row*128 + ((((kk<<2)+g) ^ (lr&7))<<3);
        bf16x8 kf = *(const bf16x8*)(&KV[cur][0][off]);
        bf16x8 kg = *(const bf16x8*)(&KV[cur][1][off]);
        s[nf] = __builtin_amdgcn_mfma_f32_16x16x32_bf16(qfh[kk], kf, s[nf],0,0,0);
        s[nf] = __builtin_amdgcn_mfma_f32_16x16x32_bf16(qfh[kk], kg, s[nf],0,0,0);
        s[nf] = __builtin_amdgcn_mfma_f32_16x16x32_bf16(qfl[kk], kf, s[nf],0,0,0);
      }
    }
    __builtin_amdgcn_s_setprio(0);

    // ---- online softmax ----
    float sv[4][4], pm[4];
    #pragma unroll
    for (int i=0;i<4;i++) pm[i] = -3e38f;
    bool diag = (kt == qt);
    #pragma unroll
    for (int nf=0;nf<4;nf++)
      #pragma unroll
      for (int i=0;i<4;i++){
        float v = s[nf][i] * 0.08838834764831845f;
        if (diag && (kvb + nf*16 + lr > q0 + g*4 + i)) v = -1e30f;
        sv[nf][i] = v;
        pm[i] = fmaxf(pm[i], v);
      }
    #pragma unroll
    for (int i=0;i<4;i++)
      #pragma unroll
      for (int d=1; d<16; d<<=1) pm[i] = fmaxf(pm[i], __shfl_xor(pm[i], d));
    float sf[4], psum[4];
    #pragma unroll
    for (int i=0;i<4;i++){
      float nm = fmaxf(mreg[i], pm[i]);
      sf[i] = __expf(mreg[i] - nm);
      mreg[i] = nm; psum[i] = 0.f;
    }
    #pragma unroll
    for (int nf=0;nf<4;nf++)
      #pragma unroll
      for (int i=0;i<4;i++){
        float e = __expf(sv[nf][i] - mreg[i]);
        sv[nf][i] = e; psum[i] += e;
      }
    #pragma unroll
    for (int i=0;i<4;i++){
      #pragma unroll
      for (int d=1; d<16; d<<=1) psum[i] += __shfl_xor(psum[i], d);
      lsum[i] = lsum[i]*sf[i] + psum[i];
    }
    #pragma unroll
    for (int nf=0;nf<8;nf++)
      #pragma unroll
      for (int i=0;i<4;i++) o[nf][i] *= sf[i];

    // ---- P round-trip (per-wave LDS, no barrier needed) ----
    #pragma unroll
    for (int nf=0;nf<4;nf++)
      #pragma unroll
      for (int i=0;i<4;i++){
        int qi = g*4 + i, kv = nf*16 + lr;
        int idx = qi*64 + (kv ^ ((qi&7)<<3));
        u16 hb = f2b(sv[nf][i]);
        Ph[w][idx] = hb;
        Pl[w][idx] = f2b(sv[nf][i] - b2f(hb));
      }

    // ---- PV (3-pass split) from LDS ----
    #pragma unroll
    for (int kk2=0; kk2<2; kk2++){
      int pidx = lr*64 + ((kk2*32 + g*8) ^ ((lr&7)<<3));
      bf16x8 ph = *(const bf16x8*)(&Ph[w][pidx]);
      bf16x8 pl = *(const bf16x8*)(&Pl[w][pidx]);
      __builtin_amdgcn_s_setprio(1);
      #pragma unroll
      for (int nf=0; nf<8; nf++){
        int row = nf*16 + lr;
        int off = row*64 + ((((kk2<<2)+g) ^ (lr&7))<<3);
        bf16x8 vf = *(const bf16x8*)(&KV[cur][2][off]);
        bf16x8 vg = *(const bf16x8*)(&KV[cur][3][off]);
        o[nf] = __builtin_amdgcn_mfma_f32_16x16x32_bf16(ph, vf, o[nf],0,0,0);
        o[nf] = __builtin_amdgcn_mfma_f32_16x16x32_bf16(ph, vg, o[nf],0,0,0);
        o[nf] = __builtin_amdgcn_mfma_f32_16x16x32_bf16(pl, vf, o[nf],0,0,0);
      }
      __builtin_amdgcn_s_setprio(0);
    }
    __builtin_amdgcn_s_barrier();   // all waves done with buf[cur] before overwrite
  }

  float inv[4];
  #pragma unroll
  for (int i=0;i<4;i++) inv[i] = 1.0f / lsum[i];
  #pragma unroll
  for (int nf=0;nf<8;nf++)
    #pragma unroll
    for (int i=0;i<4;i++){
      float v = o[nf][i] * inv[i];
      size_t oidx = (size_t)(q0 + g*4 + i)*2048 + head*HD + nf*16 + lr;
      u16 hb = f2b(v);
      oh_[oidx] = hb; ol_[oidx] = f2b(v - b2f(hb));
    }
}

// ---------------- router: fp32 logits, top-2, renorm ----------------
__global__ __launch_bounds__(256) void mx_router(
    const float* __restrict__ h2, const float* __restrict__ gw,
    int* __restrict__ meta, int* __restrict__ tki, float* __restrict__ tkw)
{
  int t = blockIdx.x, tid = threadIdx.x;
  float p[8] = {0,0,0,0,0,0,0,0};
  const float* row = h2 + (size_t)t*H_;
  for (int i = tid; i < H_; i += 256) {
    float x = row[i];
    #pragma unroll
    for (int e=0;e<8;e++) p[e] += x * gw[e*H_ + i];
  }
  #pragma unroll
  for (int e=0;e<8;e++)
    #pragma unroll
    for (int d=32; d; d>>=1) p[e] += __shfl_down(p[e], d);
  __shared__ float red[4][8];
  int w = tid>>6;
  if ((tid&63)==0){
    #pragma unroll
    for (int e=0;e<8;e++) red[w][e] = p[e];
  }
  __syncthreads();
  if (tid==0){
    float lg[8];
    #pragma unroll
    for (int e=0;e<8;e++) lg[e] = red[0][e]+red[1][e]+red[2][e]+red[3][e];
    int e0 = 0;
    for (int e=1;e<8;e++) if (lg[e] > lg[e0]) e0 = e;
    int e1 = (e0==0)?1:0;
    for (int e=0;e<8;e++) if (e!=e0 && lg[e] > lg[e1]) e1 = e;
    float w0 = 1.f/(1.f + __expf(lg[e1]-lg[e0]));
    tki[t*2]=e0; tki[t*2+1]=e1; tkw[t*2]=w0; tkw[t*2+1]=1.f-w0;
    atomicAdd(&meta[e0],1); atomicAdd(&meta[e1],1);
  }
}

// meta: [0..7]=counts [8..15]=poff [16..23]=ptiles [24..31]=cursor; gsh = tile granularity shift
__global__ void mx_scan(int* __restrict__ meta, int* __restrict__ perm, int gsh)
{
  if (threadIdx.x == 0){
    int run = 0;
    for (int e=0;e<8;e++){
      meta[8+e] = run;
      int pt = (meta[e] + (1<<gsh) - 1) >> gsh;
      meta[16+e] = pt;
      run += pt << gsh;
      meta[24+e] = 0;
    }
  }
  for (int i = threadIdx.x; i < PROWS; i += 256) perm[i] = 0;
}

__global__ void mx_scatter(const int* __restrict__ tki, int* __restrict__ meta,
                           int* __restrict__ perm, int* __restrict__ slot)
{
  int t = blockIdx.x*256 + threadIdx.x;
  if (t >= T_) return;
  #pragma unroll
  for (int j=0;j<2;j++){
    int e = tki[t*2+j];
    int s = atomicAdd(&meta[24+e], 1);
    int pos = meta[8+e] + s;
    perm[pos] = t;
    slot[t*2+j] = pos;
  }
}

__global__ void mx_combine(const float* __restrict__ Y2, const int* __restrict__ slot,
                           const float* __restrict__ tkw, float* __restrict__ out)
{
  int t = blockIdx.x, tid = threadIdx.x;
  int s0 = slot[t*2], s1 = slot[t*2+1];
  float w0 = tkw[t*2], w1 = tkw[t*2+1];
  const float4* r0 = (const float4*)(Y2 + (size_t)s0*H_);
  const float4* r1 = (const float4*)(Y2 + (size_t)s1*H_);
  float4* o4 = (float4*)(out + (size_t)t*H_);
  for (int i = tid; i < 512; i += 256){
    float4 a = r0[i], b = r1[i], c;
    c.x = w0*a.x + w1*b.x; c.y = w0*a.y + w1*b.y;
    c.z = w0*a.z + w1*b.z; c.w = w0*a.w + w1*b.w;
    o4[i] = c;
  }
}

extern "C" void kernel_launch(void* const* d_in, const int* in_sizes, int n_in,
                              void* d_out, int out_size, void* d_ws, size_t ws_size,
                              hipStream_t stream)
{
  (void)in_sizes; (void)n_in; (void)out_size;
  const int*   positions = (const int*)  d_in[0];
  const float* hidden    = (const float*)d_in[1];
  const float* residual  = (const float*)d_in[2];
  const float* ln1       = (const float*)d_in[3];
  const float* ln2       = (const float*)d_in[4];
  const float* wq        = (const float*)d_in[5];
  const float* wk        = (const float*)d_in[6];
  const float* wv        = (const float*)d_in[7];
  const float* wo        = (const float*)d_in[8];
  const float* gatew     = (const float*)d_in[9];
  const float* w1        = (const float*)d_in[10];
  const float* w3        = (const float*)d_in[11];
  const float* w2        = (const float*)d_in[12];
  float* outp = (float*)d_out;                 // [T*H] moe out, then [T*H] residual
  char* ws = (char*)d_ws;

  size_t off = 0;
  auto alloc = [&](size_t n){ size_t o = off; off += (n + 255) & ~(size_t)255; return o; };
  float* cosT = (float*)(ws + alloc((size_t)T_*64*4));
  float* sinT = (float*)(ws + alloc((size_t)T_*64*4));
  size_t res1_off = alloc((size_t)T_*H_*4);
  float* res1 = (float*)(ws + res1_off);
  u16*   h1h  = (u16*)  (ws + alloc((size_t)T_*H_*2));
  u16*   h1l  = (u16*)  (ws + alloc((size_t)T_*H_*2));
  float* qkvF = (float*)(ws + alloc((size_t)T_*3072*4));
  size_t qh_off = alloc((size_t)NH*T_*HD*2);
  u16*   qh   = (u16*)  (ws + qh_off);
  u16*   ql   = (u16*)  (ws + alloc((size_t)NH*T_*HD*2));
  u16*   kh   = (u16*)  (ws + alloc((size_t)NKV*T_*HD*2));
  u16*   kl   = (u16*)  (ws + alloc((size_t)NKV*T_*HD*2));
  u16*   vh   = (u16*)  (ws + alloc((size_t)NKV*T_*HD*2));
  u16*   vl   = (u16*)  (ws + alloc((size_t)NKV*T_*HD*2));
  u16*   aoh  = (u16*)  (ws + alloc((size_t)T_*2048*2));
  u16*   aol  = (u16*)  (ws + alloc((size_t)T_*2048*2));
  float* oF   = (float*)(ws + alloc((size_t)T_*H_*4));
  float* h2f  = (float*)(ws + alloc((size_t)T_*H_*4));
  u16*   h2b  = (u16*)  (ws + alloc((size_t)T_*H_*2));
  int*   meta = (int*)  (ws + alloc(32*4));
  int*   tki  = (int*)  (ws + alloc((size_t)T_*2*4));
  float* tkw  = (float*)(ws + alloc((size_t)T_*2*4));
  int*   slot = (int*)  (ws + alloc((size_t)T_*2*4));
  int*   perm = (int*)  (ws + alloc((size_t)PROWS*4));
  u16*   Y1   = (u16*)  (ws + alloc((size_t)PROWS*II_*2));
  // Y2 aliases qh..oF (dead before the w2 GEMM)
  float* Y2   = (float*)(ws + qh_off);
  // bf16 weight copies — gated on ws_size (fallback path removed; big ws guaranteed in practice)
  u16* w1b = (u16*)(ws + alloc((size_t)NE*II_*H_*2));
  u16* w3b = (u16*)(ws + alloc((size_t)NE*II_*H_*2));
  u16* w2b = (u16*)(ws + alloc((size_t)NE*H_*II_*2));
  u16* qwh = (u16*)(ws + alloc((size_t)3072*H_*2));   // wq|wk|wv rows concat, split-hi
  u16* qwl = (u16*)(ws + alloc((size_t)3072*H_*2));
  u16* woh = (u16*)(ws + alloc((size_t)H_*H_*2));
  u16* wol = (u16*)(ws + alloc((size_t)H_*H_*2));

  // 0. weight conversions
  int n8 = NE*II_*H_/8;
  mx_cvt<<<2048, 256, 0, stream>>>(w1, w1b, n8);
  mx_cvt<<<2048, 256, 0, stream>>>(w3, w3b, n8);
  mx_cvt<<<2048, 256, 0, stream>>>(w2, w2b, n8);
  mx_cvt_split<<<512, 256, 0, stream>>>(wq, qwh,             qwl,             2048*2048/8);
  mx_cvt_split<<<512, 256, 0, stream>>>(wk, qwh + 2048*2048, qwl + 2048*2048, 512*2048/8);
  mx_cvt_split<<<512, 256, 0, stream>>>(wv, qwh + 2560*2048, qwl + 2560*2048, 512*2048/8);
  mx_cvt_split<<<512, 256, 0, stream>>>(wo, woh,             wol,             2048*2048/8);
  // 1. RoPE tables + fused add+norm1
  mx_rope_table<<<512, 256, 0, stream>>>(positions, cosT, sinT);
  mx_addnorm<<<T_, 256, 0, stream>>>(hidden, residual, ln1, res1, h1h, h1l,
                                     nullptr, nullptr, nullptr);
  // 2. QKV projection (3-pass split, fused single launch)
  mx_gemm3g<16,24><<<384, 256, 0, stream>>>(h1h, h1l, qwh, qwl, qkvF, 3072, H_);
  // 3. RoPE apply + V transpose
  mx_rope_apply<<<dim3(T_/4, NH+NKV), 256, 0, stream>>>(qkvF, cosT, sinT, qh, ql, kh, kl);
  mx_transpose_v<<<dim3(NKV, T_/64), 256, 0, stream>>>(qkvF, vh, vl);
  // 4. attention (2 heads/block, 8 waves, dbuf 160KB, counted vmcnt)
  mx_attn<<<dim3(T_/64, 8), 512, 0, stream>>>(qh, ql, kh, kl, vh, vl, aoh, aol);
  // 5. o_proj (3-pass split)
  mx_gemm3g<16,16><<<256, 256, 0, stream>>>(aoh, aol, woh, wol, oF, 2048, 2048);
  // 6. add + norm2 (residual output + h2 fp32 + h2 bf16); zero expert counts
  mx_addnorm<<<T_, 256, 0, stream>>>(oF, res1, ln2, outp + (size_t)T_*H_,
                                     nullptr, nullptr, h2f, h2b, meta);
  // 7. router + routing metadata
  mx_router<<<T_, 256, 0, stream>>>(h2f, gatew, meta, tki, tkw);
  mx_scan<<<1, 256, 0, stream>>>(meta, perm, 7);
  mx_scatter<<<T_/256, 256, 0, stream>>>(tki, meta, perm, slot);
  // 8. MoE expert GEMMs
  mx_moe_w13<32><<<4096, 256, 0, stream>>>(h2b, w1b, w3b, Y1, perm, meta);
  mx_moe_w2k<16><<<2048, 256, 0, stream>>>(Y1, w2b, Y2, meta);
  // 9. combine weighted expert outputs -> out
  mx_combine<<<T_, 256, 0, stream>>>(Y2, slot, tkw, outp);
  (void)ws_size;
}

// Round 12
// 1009.311 us; speedup vs baseline: 1.2742x; 1.0166x over previous
//
#include <hip/hip_runtime.h>
#include <hip/hip_bf16.h>
#include <math.h>

// Mixtral decoder layer, MI355X. T=2048 H=2048 NH=16 NKV=4 HD=128 I=4096 E=8 TOPK=2.
// Pre-router path (QKV, attn, o_proj): 3-pass bf16-split MFMA (~fp32 accurate) so the
// router top-k matches the fp32 reference; MoE expert path is plain bf16.
// R12: the three big fp32->bf16 weight conversions are folded into the attention
// kernel's grid as helper blocks (y>=8) that backfill CUs idled by causal imbalance.

#define T_  2048
#define H_  2048
#define NH  16
#define NKV 4
#define HD  128
#define II_ 4096
#define NE  8
#define EPS 1e-5f
#define PROWS 6144   // padded permuted rows

typedef __bf16 bf16x8 __attribute__((ext_vector_type(8)));
typedef float  f32x4  __attribute__((ext_vector_type(4)));
typedef unsigned short u16;

__device__ __forceinline__ u16 f2b(float f){ __bf16 b = (__bf16)f; return __builtin_bit_cast(u16, b); }
__device__ __forceinline__ float b2f(u16 u){ return (float)__builtin_bit_cast(__bf16, u); }

__device__ __forceinline__ void gll16(const void* g, void* l){
  __builtin_amdgcn_global_load_lds(
      (const __attribute__((address_space(1))) unsigned int*)g,
      (__attribute__((address_space(3))) unsigned int*)l, 16, 0, 0);
}

// ---------------- fp32 -> split (hi, lo) bf16 conversion ----------------
__global__ __launch_bounds__(256) void mx_cvt_split(const float* __restrict__ s,
                                                    u16* __restrict__ hi,
                                                    u16* __restrict__ lo, int n8)
{
  int i = blockIdx.x*256 + threadIdx.x;
  int stride = gridDim.x*256;
  for (; i < n8; i += stride){
    const f32x4* p = (const f32x4*)s + 2*(size_t)i;
    f32x4 a = p[0], b = p[1];
    uint4 uh, ul;
    u16 h0,h1,h2,h3;
    h0=f2b(a[0]); h1=f2b(a[1]); h2=f2b(a[2]); h3=f2b(a[3]);
    uh.x = (unsigned)h0 | ((unsigned)h1<<16);
    uh.y = (unsigned)h2 | ((unsigned)h3<<16);
    ul.x = (unsigned)f2b(a[0]-b2f(h0)) | ((unsigned)f2b(a[1]-b2f(h1))<<16);
    ul.y = (unsigned)f2b(a[2]-b2f(h2)) | ((unsigned)f2b(a[3]-b2f(h3))<<16);
    h0=f2b(b[0]); h1=f2b(b[1]); h2=f2b(b[2]); h3=f2b(b[3]);
    uh.z = (unsigned)h0 | ((unsigned)h1<<16);
    uh.w = (unsigned)h2 | ((unsigned)h3<<16);
    ul.z = (unsigned)f2b(b[0]-b2f(h0)) | ((unsigned)f2b(b[1]-b2f(h1))<<16);
    ul.w = (unsigned)f2b(b[2]-b2f(h2)) | ((unsigned)f2b(b[3]-b2f(h3))<<16);
    ((uint4*)hi)[i] = uh;
    ((uint4*)lo)[i] = ul;
  }
}

// ---------------- RoPE cos/sin table (double-precision inv_freq) ----------------
__global__ void mx_rope_table(const int* __restrict__ pos, float* __restrict__ cosT,
                              float* __restrict__ sinT)
{
  int i = blockIdx.x*256 + threadIdx.x;            // T*64
  int t = i >> 6, d = i & 63;
  float inv = (float)exp(-((double)d/64.0) * 9.210340371976184); // 10000^{-d/64}
  float f = (float)pos[t] * inv;
  cosT[i] = cosf(f); sinT[i] = sinf(f);
}

// ---------------- fused add + RMSNorm (writes several output forms) ----------------
__global__ __launch_bounds__(256) void mx_addnorm(
    const float* __restrict__ a, const float* __restrict__ b,
    const float* __restrict__ gam, float* __restrict__ res_out,
    u16* __restrict__ hi, u16* __restrict__ lo,
    float* __restrict__ hf, u16* __restrict__ hbf, int* __restrict__ mz)
{
  int t = blockIdx.x, tid = threadIdx.x;
  if (mz && t == 0 && tid < 8) mz[tid] = 0;
  const float4* A4 = (const float4*)a + (size_t)t*512;
  const float4* B4 = (const float4*)b + (size_t)t*512;
  float4 va = A4[tid], vb = B4[tid];
  float4 x0; x0.x=va.x+vb.x; x0.y=va.y+vb.y; x0.z=va.z+vb.z; x0.w=va.w+vb.w;
  va = A4[tid+256]; vb = B4[tid+256];
  float4 x1; x1.x=va.x+vb.x; x1.y=va.y+vb.y; x1.z=va.z+vb.z; x1.w=va.w+vb.w;
  float ss = x0.x*x0.x + x0.y*x0.y + x0.z*x0.z + x0.w*x0.w
           + x1.x*x1.x + x1.y*x1.y + x1.z*x1.z + x1.w*x1.w;
  #pragma unroll
  for (int d=32; d; d>>=1) ss += __shfl_down(ss, d);
  __shared__ float red[4];
  if ((tid&63)==0) red[tid>>6] = ss;
  __syncthreads();
  ss = red[0]+red[1]+red[2]+red[3];
  float scale = rsqrtf(ss * (1.f/2048.f) + EPS);
  float4* R4 = (float4*)res_out + (size_t)t*512;
  R4[tid] = x0; R4[tid+256] = x1;
  const float4* G4p = (const float4*)gam;
  float4 g0 = G4p[tid], g1 = G4p[tid+256];
  float4 y0; y0.x=x0.x*scale*g0.x; y0.y=x0.y*scale*g0.y; y0.z=x0.z*scale*g0.z; y0.w=x0.w*scale*g0.w;
  float4 y1; y1.x=x1.x*scale*g1.x; y1.y=x1.y*scale*g1.y; y1.z=x1.z*scale*g1.z; y1.w=x1.w*scale*g1.w;
  if (hf){ float4* H4 = (float4*)hf + (size_t)t*512; H4[tid]=y0; H4[tid+256]=y1; }
  if (hi){
    ushort4 uh, ul;
    uh.x=f2b(y0.x); ul.x=f2b(y0.x-b2f(uh.x));
    uh.y=f2b(y0.y); ul.y=f2b(y0.y-b2f(uh.y));
    uh.z=f2b(y0.z); ul.z=f2b(y0.z-b2f(uh.z));
    uh.w=f2b(y0.w); ul.w=f2b(y0.w-b2f(uh.w));
    ((ushort4*)hi)[(size_t)t*512 + tid] = uh; ((ushort4*)lo)[(size_t)t*512 + tid] = ul;
    uh.x=f2b(y1.x); ul.x=f2b(y1.x-b2f(uh.x));
    uh.y=f2b(y1.y); ul.y=f2b(y1.y-b2f(uh.y));
    uh.z=f2b(y1.z); ul.z=f2b(y1.z-b2f(uh.z));
    uh.w=f2b(y1.w); ul.w=f2b(y1.w-b2f(uh.w));
    ((ushort4*)hi)[(size_t)t*512 + tid+256] = uh; ((ushort4*)lo)[(size_t)t*512 + tid+256] = ul;
  }
  if (hbf){
    ushort4 u0; u0.x=f2b(y0.x); u0.y=f2b(y0.y); u0.z=f2b(y0.z); u0.w=f2b(y0.w);
    ushort4 u1; u1.x=f2b(y1.x); u1.y=f2b(y1.y); u1.z=f2b(y1.z); u1.w=f2b(y1.w);
    ((ushort4*)hbf)[(size_t)t*512 + tid] = u0; ((ushort4*)hbf)[(size_t)t*512 + tid+256] = u1;
  }
}

// ------- 3-pass split GEMM, gll16 m97 skeleton: C = A(hi,lo) x B(hi,lo)^T, fp32 out -------
template<int NX, int NY>
__global__ __launch_bounds__(256,2) void mx_gemm3g(
    const u16* __restrict__ Ah, const u16* __restrict__ Al,
    const u16* __restrict__ Bh, const u16* __restrict__ Bl,
    float* __restrict__ C, int ldc, int K)
{
  __shared__ u16 AhS[128*64], AlS[128*64], BhS[128*64], BlS[128*64];
  int bid = blockIdx.x;
  int xcd = bid & 7, j = bid >> 3;
  int x = j % NX, p = j / NX;
  int y = xcd + 8*p;
  int m0 = x*128, n0 = y*128;
  int tid = threadIdx.x;
  int w = tid>>6, lane = tid&63, wr = w>>1, wc = w&1, g = lane>>4, lr = lane&15;
  f32x4 acc[4][4];
  #pragma unroll
  for (int fm=0;fm<4;fm++)
    #pragma unroll
    for (int fn=0;fn<4;fn++) acc[fm][fn] = (f32x4){0.f,0.f,0.f,0.f};

  for (int k0 = 0; k0 < K; k0 += 64) {
    #pragma unroll
    for (int i=0;i<4;i++){
      int c = i*256 + tid, r = c>>3, ch = c&7;
      int sw = ((ch ^ (r&7))<<3);
      int db = (i*256 + w*64)<<3;
      gll16(Ah + (size_t)(m0+r)*K + k0 + sw, &AhS[db]);
      gll16(Al + (size_t)(m0+r)*K + k0 + sw, &AlS[db]);
      gll16(Bh + (size_t)(n0+r)*K + k0 + sw, &BhS[db]);
      gll16(Bl + (size_t)(n0+r)*K + k0 + sw, &BlS[db]);
    }
    __syncthreads();
    #pragma unroll
    for (int kk=0;kk<2;kk++){
      bf16x8 ah[4], al[4], bh[4], bl[4];
      #pragma unroll
      for (int fm=0;fm<4;fm++){
        int r = wr*64 + fm*16 + lr;
        int ch = ((kk<<2)+g) ^ (r&7);
        ah[fm] = *(const bf16x8*)(&AhS[(r<<6)+(ch<<3)]);
        al[fm] = *(const bf16x8*)(&AlS[(r<<6)+(ch<<3)]);
      }
      #pragma unroll
      for (int fn=0;fn<4;fn++){
        int r = wc*64 + fn*16 + lr;
        int ch = ((kk<<2)+g) ^ (r&7);
        bh[fn] = *(const bf16x8*)(&BhS[(r<<6)+(ch<<3)]);
        bl[fn] = *(const bf16x8*)(&BlS[(r<<6)+(ch<<3)]);
      }
      __builtin_amdgcn_s_setprio(1);
      #pragma unroll
      for (int fm=0;fm<4;fm++)
        #pragma unroll
        for (int fn=0;fn<4;fn++){
          acc[fm][fn] = __builtin_amdgcn_mfma_f32_16x16x32_bf16(ah[fm], bh[fn], acc[fm][fn],0,0,0);
          acc[fm][fn] = __builtin_amdgcn_mfma_f32_16x16x32_bf16(ah[fm], bl[fn], acc[fm][fn],0,0,0);
          acc[fm][fn] = __builtin_amdgcn_mfma_f32_16x16x32_bf16(al[fm], bh[fn], acc[fm][fn],0,0,0);
        }
      __builtin_amdgcn_s_setprio(0);
    }
    __syncthreads();
  }
  #pragma unroll
  for (int fm=0;fm<4;fm++)
    #pragma unroll
    for (int fn=0;fn<4;fn++)
      #pragma unroll
      for (int i=0;i<4;i++){
        size_t rg = (size_t)(m0 + wr*64 + fm*16 + g*4 + i);
        int cg = n0 + wc*64 + fn*16 + lr;
        C[rg*ldc + cg] = acc[fm][fn][i];
      }
}

// ------------- MoE w1+w3 fused GEMM + silu epilogue (all-bf16, m97-style) -------------
template<int NY>
__global__ __launch_bounds__(256,2) void mx_moe_w13(
    const u16* __restrict__ A,
    const u16* __restrict__ B1, const u16* __restrict__ B3,
    u16* __restrict__ Y,
    const int* __restrict__ row_map, const int* __restrict__ meta)
{
  __shared__ u16 As[128*64], B1s[128*64], B3s[128*64];
  int bid = blockIdx.x;
  int xcd = bid & 7, j = bid >> 3;
  int x = j & 15, p = j >> 4;
  int panel = xcd + 8*p;                 // < NE*NY
  int e = panel / NY, y = panel % NY;
  if (x >= meta[16+e]) return;
  int rowbase = meta[8+e] + (x<<7);
  const u16* B1p = B1 + ((size_t)e*II_ + y*128)*H_;
  const u16* B3p = B3 + ((size_t)e*II_ + y*128)*H_;
  int tid = threadIdx.x;
  int w = tid>>6, lane = tid&63, wr = w>>1, wc = w&1, g = lane>>4, lr = lane&15;

  f32x4 acc1[4][4], acc3[4][4];
  #pragma unroll
  for (int fm=0;fm<4;fm++)
    #pragma unroll
    for (int fn=0;fn<4;fn++){ acc1[fm][fn]=(f32x4){0,0,0,0}; acc3[fm][fn]=(f32x4){0,0,0,0}; }

  for (int k0 = 0; k0 < H_; k0 += 64) {
    #pragma unroll
    for (int i=0;i<4;i++){
      int c = i*256 + tid, r = c>>3, ch = c&7;
      int sw = (ch ^ (r&7))<<3;
      int db = (i*256 + w*64)<<3;
      int grow = row_map[rowbase + r];
      gll16(A   + (size_t)grow*H_ + k0 + sw, &As[db]);
      gll16(B1p + (size_t)r*H_    + k0 + sw, &B1s[db]);
      gll16(B3p + (size_t)r*H_    + k0 + sw, &B3s[db]);
    }
    __syncthreads();
    #pragma unroll
    for (int kk=0;kk<2;kk++){
      bf16x8 af[4], b1f[4], b3f[4];
      #pragma unroll
      for (int fm=0;fm<4;fm++){
        int r = wr*64 + fm*16 + lr;
        int ch = ((kk<<2)+g) ^ (r&7);
        af[fm] = *(const bf16x8*)(&As[(r<<6)+(ch<<3)]);
      }
      #pragma unroll
      for (int fn=0;fn<4;fn++){
        int r = wc*64 + fn*16 + lr;
        int ch = ((kk<<2)+g) ^ (r&7);
        b1f[fn] = *(const bf16x8*)(&B1s[(r<<6)+(ch<<3)]);
        b3f[fn] = *(const bf16x8*)(&B3s[(r<<6)+(ch<<3)]);
      }
      __builtin_amdgcn_s_setprio(1);
      #pragma unroll
      for (int fm=0;fm<4;fm++)
        #pragma unroll
        for (int fn=0;fn<4;fn++){
          acc1[fm][fn] = __builtin_amdgcn_mfma_f32_16x16x32_bf16(af[fm], b1f[fn], acc1[fm][fn],0,0,0);
          acc3[fm][fn] = __builtin_amdgcn_mfma_f32_16x16x32_bf16(af[fm], b3f[fn], acc3[fm][fn],0,0,0);
        }
      __builtin_amdgcn_s_setprio(0);
    }
    __syncthreads();
  }
  int n0 = y*128 + wc*64;
  #pragma unroll
  for (int fm=0;fm<4;fm++)
    #pragma unroll
    for (int fn=0;fn<4;fn++)
      #pragma unroll
      for (int i=0;i<4;i++){
        size_t rg = (size_t)(rowbase + wr*64 + fm*16 + g*4 + i);
        int cg = n0 + fn*16 + lr;
        float gg = acc1[fm][fn][i], uu = acc3[fm][fn][i];
        float sg = gg / (1.f + __expf(-gg));
        Y[rg*II_ + cg] = f2b(sg * uu);
      }
}

// ------------- MoE w2 GEMM (all-bf16, m97-style): Y2 = Y . w2^T -------------
template<int NY>
__global__ __launch_bounds__(256,2) void mx_moe_w2k(
    const u16* __restrict__ A,       // Y bf16 [PROWS][II_]
    const u16* __restrict__ B,       // w2b bf16 [E][H_][II_]
    float* __restrict__ C,           // Y2 fp32 [PROWS][H_]
    const int* __restrict__ meta)
{
  __shared__ u16 As[128*64], Bs[128*64];
  int bid = blockIdx.x;
  int xcd = bid & 7, j = bid >> 3;
  int x = j & 15, p = j >> 4;
  int panel = xcd + 8*p;                 // < NE*NY
  int e = panel / NY, y = panel % NY;
  if (x >= meta[16+e]) return;
  int rowbase = meta[8+e] + (x<<7);
  const u16* Bp = B + ((size_t)e*H_ + y*128)*II_;
  int tid = threadIdx.x;
  int w = tid>>6, lane = tid&63, wr = w>>1, wc = w&1, g = lane>>4, lr = lane&15;

  f32x4 acc[4][4];
  #pragma unroll
  for (int fm=0;fm<4;fm++)
    #pragma unroll
    for (int fn=0;fn<4;fn++) acc[fm][fn] = (f32x4){0,0,0,0};

  for (int k0 = 0; k0 < II_; k0 += 64) {
    #pragma unroll
    for (int i=0;i<4;i++){
      int c = i*256 + tid, r = c>>3, ch = c&7;
      int sw = (ch ^ (r&7))<<3;
      int db = (i*256 + w*64)<<3;
      gll16(A  + (size_t)(rowbase + r)*II_ + k0 + sw, &As[db]);
      gll16(Bp + (size_t)r*II_             + k0 + sw, &Bs[db]);
    }
    __syncthreads();
    #pragma unroll
    for (int kk=0;kk<2;kk++){
      bf16x8 af[4], bf[4];
      #pragma unroll
      for (int fm=0;fm<4;fm++){
        int r = wr*64 + fm*16 + lr;
        int ch = ((kk<<2)+g) ^ (r&7);
        af[fm] = *(const bf16x8*)(&As[(r<<6)+(ch<<3)]);
      }
      #pragma unroll
      for (int fn=0;fn<4;fn++){
        int r = wc*64 + fn*16 + lr;
        int ch = ((kk<<2)+g) ^ (r&7);
        bf[fn] = *(const bf16x8*)(&Bs[(r<<6)+(ch<<3)]);
      }
      __builtin_amdgcn_s_setprio(1);
      #pragma unroll
      for (int fm=0;fm<4;fm++)
        #pragma unroll
        for (int fn=0;fn<4;fn++)
          acc[fm][fn] = __builtin_amdgcn_mfma_f32_16x16x32_bf16(af[fm], bf[fn], acc[fm][fn],0,0,0);
      __builtin_amdgcn_s_setprio(0);
    }
    __syncthreads();
  }
  int n0 = y*128 + wc*64;
  #pragma unroll
  for (int fm=0;fm<4;fm++)
    #pragma unroll
    for (int fn=0;fn<4;fn++)
      #pragma unroll
      for (int i=0;i<4;i++){
        size_t rg = (size_t)(rowbase + wr*64 + fm*16 + g*4 + i);
        int cg = n0 + fn*16 + lr;
        C[rg*H_ + cg] = acc[fm][fn][i];
      }
}

// ---------------- RoPE apply: qkv fp32 -> split-bf16 Q [h][t][d], K [kv][t][d] ----------------
__global__ __launch_bounds__(256) void mx_rope_apply(const float* __restrict__ qkv,
    const float* __restrict__ cosT, const float* __restrict__ sinT,
    u16* __restrict__ qh, u16* __restrict__ ql, u16* __restrict__ kh, u16* __restrict__ kl)
{
  int t = blockIdx.x*4 + (threadIdx.x>>6);
  int hh = blockIdx.y, d = threadIdx.x & 63;
  const float* row = qkv + (size_t)t*3072;
  float c = cosT[t*64+d], s = sinT[t*64+d];
  float x1, x2; size_t base; u16 *oh, *ol;
  if (hh < NH){ x1 = row[hh*HD+d]; x2 = row[hh*HD+d+64];
     base = ((size_t)hh*T_ + t)*HD; oh = qh; ol = ql; }
  else { int kvh = hh-NH; x1 = row[2048 + kvh*HD + d]; x2 = row[2048 + kvh*HD + d + 64];
     base = ((size_t)kvh*T_ + t)*HD; oh = kh; ol = kl; }
  float o1 = x1*c - x2*s, o2 = x2*c + x1*s;
  u16 a = f2b(o1); oh[base+d]    = a; ol[base+d]    = f2b(o1 - b2f(a));
  u16 b = f2b(o2); oh[base+d+64] = b; ol[base+d+64] = f2b(o2 - b2f(b));
}

// ---------------- V transpose: qkv fp32 -> split-bf16 V^T [kv][d][t] ----------------
__global__ void mx_transpose_v(const float* __restrict__ qkv,
                               u16* __restrict__ vh, u16* __restrict__ vl)
{
  __shared__ float tile[64][132];
  int kv = blockIdx.x, t0 = blockIdx.y*64, tid = threadIdx.x;
  #pragma unroll
  for (int it=0; it<32; ++it){
    int idx = it*256 + tid; int r = idx>>7, d = idx&127;
    tile[r][d] = qkv[(size_t)(t0+r)*3072 + 2560 + kv*HD + d];
  }
  __syncthreads();
  #pragma unroll
  for (int it=0; it<32; ++it){
    int idx = it*256 + tid; int d = idx>>6, j = idx&63;
    float x = tile[j][d];
    u16 a = f2b(x);
    size_t o = ((size_t)kv*HD + d)*T_ + t0 + j;
    vh[o] = a; vl[o] = f2b(x - b2f(a));
  }
}

// ---------------- flash attention (y<8) + weight-cvt helper blocks (y>=8) ----------------
// Attention: 2 heads/block, 8 waves, dbuf 160KB LDS, counted vmcnt(8) (R11-proven).
// Helpers: grid-stride fp32->bf16 conversion of w1/w3/w2 — they backfill CUs idled by
// causal imbalance (attn blocks dispatch first: lower linear IDs).
__global__ __launch_bounds__(512) void mx_attn(
  const u16* __restrict__ qh_, const u16* __restrict__ ql_,
  const u16* __restrict__ kh_, const u16* __restrict__ kl_,
  const u16* __restrict__ vh_, const u16* __restrict__ vl_,
  u16* __restrict__ oh_, u16* __restrict__ ol_,
  const float* __restrict__ w1f, const float* __restrict__ w3f,
  const float* __restrict__ w2f,
  u16* __restrict__ w1b, u16* __restrict__ w3b, u16* __restrict__ w2b)
{
  if (blockIdx.y >= 8){
    // -------- cvt helper path (no LDS, no barriers) --------
    const int n8 = NE*II_*H_/8;                       // 8388608 per matrix
    int hb = (blockIdx.y - 8)*gridDim.x + blockIdx.x; // 0..3839
    int i  = hb*512 + threadIdx.x;
    const int stride = 3840*512;
    for (; i < 3*n8; i += stride){
      const float* s; u16* d; int j;
      if (i < n8)        { s = w1f; d = w1b; j = i; }
      else if (i < 2*n8) { s = w3f; d = w3b; j = i - n8; }
      else               { s = w2f; d = w2b; j = i - 2*n8; }
      const f32x4* p = (const f32x4*)s + 2*(size_t)j;
      f32x4 a = p[0], b = p[1];
      uint4 u;
      u.x = (unsigned)f2b(a[0]) | ((unsigned)f2b(a[1])<<16);
      u.y = (unsigned)f2b(a[2]) | ((unsigned)f2b(a[3])<<16);
      u.z = (unsigned)f2b(b[0]) | ((unsigned)f2b(b[1])<<16);
      u.w = (unsigned)f2b(b[2]) | ((unsigned)f2b(b[3])<<16);
      ((uint4*)d)[j] = u;
    }
    return;
  }

  int pair = blockIdx.y;                    // 0..7 -> heads (2p, 2p+1)
  int kvh = pair >> 1;
  int qt = (pair & 4) ? (31 - (int)blockIdx.x) : (int)blockIdx.x;
  int tid = threadIdx.x, w = tid>>6, lane = tid&63, g = lane>>4, lr = lane&15;
  int head = pair*2 + (w>>2);
  int q0 = qt*64 + (w&3)*16;
  __shared__ u16 KV[2][4][8192];            // [buf][Kh,Kl,Vh,Vl] 128 KB
  __shared__ u16 Ph[8][1024], Pl[8][1024];  // 32 KB (per-wave)

  bf16x8 qfh[4], qfl[4];
  const u16* qrh = qh_ + ((size_t)head*T_ + q0 + lr)*HD;
  const u16* qrl = ql_ + ((size_t)head*T_ + q0 + lr)*HD;
  #pragma unroll
  for (int kk=0;kk<4;kk++){
    qfh[kk] = *(const bf16x8*)(qrh + kk*32 + g*8);
    qfl[kk] = *(const bf16x8*)(qrl + kk*32 + g*8);
  }
  f32x4 o[8];
  #pragma unroll
  for (int nf=0;nf<8;nf++) o[nf] = (f32x4){0.f,0.f,0.f,0.f};
  float mreg[4] = {-3e38f,-3e38f,-3e38f,-3e38f}, lsum[4] = {0.f,0.f,0.f,0.f};

  const u16* kbase = kh_ + (size_t)kvh*T_*HD;
  const u16* lbase = kl_ + (size_t)kvh*T_*HD;
  const u16* vbase = vh_ + (size_t)kvh*HD*T_;
  const u16* wbase = vl_ + (size_t)kvh*HD*T_;

  auto stage = [&](int buf, int kvb){
    #pragma unroll
    for (int i=0;i<2;i++){
      int cb = i*512 + w*64;                // wave-uniform chunk base (0..1023)
      int c  = cb + lane;
      int kr = c>>4, kc = ((c&15) ^ (kr&7))<<3;
      gll16(kbase + (size_t)(kvb+kr)*HD + kc, &KV[buf][0][cb*8]);
      gll16(lbase + (size_t)(kvb+kr)*HD + kc, &KV[buf][1][cb*8]);
      int vr = c>>3, vc = ((c&7) ^ (vr&7))<<3;
      gll16(vbase + (size_t)vr*T_ + kvb + vc, &KV[buf][2][cb*8]);
      gll16(wbase + (size_t)vr*T_ + kvb + vc, &KV[buf][3][cb*8]);
    }
  };

  stage(0, 0);      // prologue: 8 loads/thread in flight

  for (int kt = 0; kt <= qt; ++kt) {
    int cur = kt & 1;
    int kvb = kt*64;
    if (kt < qt) {
      stage(cur^1, kvb+64);
      asm volatile("s_waitcnt vmcnt(8)" ::: "memory");   // cur tile landed, next in flight
    } else {
      asm volatile("s_waitcnt vmcnt(0)" ::: "memory");
    }
    __builtin_amdgcn_s_barrier();

    // ---- QK^T (3-pass split) from LDS ----
    f32x4 s[4];
    #pragma unroll
    for (int nf=0;nf<4;nf++) s[nf] = (f32x4){0.f,0.f,0.f,0.f};
    __builtin_amdgcn_s_setprio(1);
    #pragma unroll
    for (int nf=0; nf<4; nf++){
      int row = nf*16 + lr;
      #pragma unroll
      for (int kk=0;kk<4;kk++){
        int off = row*128 + ((((kk<<2)+g) ^ (lr&7))<<3);
        bf16x8 kf = *(const bf16x8*)(&KV[cur][0][off]);
        bf16x8 kg = *(const bf16x8*)(&KV[cur][1][off]);
        s[nf] = __builtin_amdgcn_mfma_f32_16x16x32_bf16(qfh[kk], kf, s[nf],0,0,0);
        s[nf] = __builtin_amdgcn_mfma_f32_16x16x32_bf16(qfh[kk], kg, s[nf],0,0,0);
        s[nf] = __builtin_amdgcn_mfma_f32_16x16x32_bf16(qfl[kk], kf, s[nf],0,0,0);
      }
    }
    __builtin_amdgcn_s_setprio(0);

    // ---- online softmax ----
    float sv[4][4], pm[4];
    #pragma unroll
    for (int i=0;i<4;i++) pm[i] = -3e38f;
    bool diag = (kt == qt);
    #pragma unroll
    for (int nf=0;nf<4;nf++)
      #pragma unroll
      for (int i=0;i<4;i++){
        float v = s[nf][i] * 0.08838834764831845f;
        if (diag && (kvb + nf*16 + lr > q0 + g*4 + i)) v = -1e30f;
        sv[nf][i] = v;
        pm[i] = fmaxf(pm[i], v);
      }
    #pragma unroll
    for (int i=0;i<4;i++)
      #pragma unroll
      for (int d=1; d<16; d<<=1) pm[i] = fmaxf(pm[i], __shfl_xor(pm[i], d));
    float sf[4], psum[4];
    #pragma unroll
    for (int i=0;i<4;i++){
      float nm = fmaxf(mreg[i], pm[i]);
      sf[i] = __expf(mreg[i] - nm);
      mreg[i] = nm; psum[i] = 0.f;
    }
    #pragma unroll
    for (int nf=0;nf<4;nf++)
      #pragma unroll
      for (int i=0;i<4;i++){
        float e = __expf(sv[nf][i] - mreg[i]);
        sv[nf][i] = e; psum[i] += e;
      }
    #pragma unroll
    for (int i=0;i<4;i++){
      #pragma unroll
      for (int d=1; d<16; d<<=1) psum[i] += __shfl_xor(psum[i], d);
      lsum[i] = lsum[i]*sf[i] + psum[i];
    }
    #pragma unroll
    for (int nf=0;nf<8;nf++)
      #pragma unroll
      for (int i=0;i<4;i++) o[nf][i] *= sf[i];

    // ---- P round-trip (per-wave LDS, no barrier needed) ----
    #pragma unroll
    for (int nf=0;nf<4;nf++)
      #pragma unroll
      for (int i=0;i<4;i++){
        int qi = g*4 + i, kv = nf*16 + lr;
        int idx = qi*64 + (kv ^ ((qi&7)<<3));
        u16 hb = f2b(sv[nf][i]);
        Ph[w][idx] = hb;
        Pl[w][idx] = f2b(sv[nf][i] - b2f(hb));
      }

    // ---- PV (3-pass split) from LDS ----
    #pragma unroll
    for (int kk2=0; kk2<2; kk2++){
      int pidx = lr*64 + ((kk2*32 + g*8) ^ ((lr&7)<<3));
      bf16x8 ph = *(const bf16x8*)(&Ph[w][pidx]);
      bf16x8 pl = *(const bf16x8*)(&Pl[w][pidx]);
      __builtin_amdgcn_s_setprio(1);
      #pragma unroll
      for (int nf=0; nf<8; nf++){
        int row = nf*16 + lr;
        int off = row*64 + ((((kk2<<2)+g) ^ (lr&7))<<3);
        bf16x8 vf = *(const bf16x8*)(&KV[cur][2][off]);
        bf16x8 vg = *(const bf16x8*)(&KV[cur][3][off]);
        o[nf] = __builtin_amdgcn_mfma_f32_16x16x32_bf16(ph, vf, o[nf],0,0,0);
        o[nf] = __builtin_amdgcn_mfma_f32_16x16x32_bf16(ph, vg, o[nf],0,0,0);
        o[nf] = __builtin_amdgcn_mfma_f32_16x16x32_bf16(pl, vf, o[nf],0,0,0);
      }
      __builtin_amdgcn_s_setprio(0);
    }
    __builtin_amdgcn_s_barrier();   // all waves done with buf[cur] before overwrite
  }

  float inv[4];
  #pragma unroll
  for (int i=0;i<4;i++) inv[i] = 1.0f / lsum[i];
  #pragma unroll
  for (int nf=0;nf<8;nf++)
    #pragma unroll
    for (int i=0;i<4;i++){
      float v = o[nf][i] * inv[i];
      size_t oidx = (size_t)(q0 + g*4 + i)*2048 + head*HD + nf*16 + lr;
      u16 hb = f2b(v);
      oh_[oidx] = hb; ol_[oidx] = f2b(v - b2f(hb));
    }
}

// ---------------- router: fp32 logits, top-2, renorm ----------------
__global__ __launch_bounds__(256) void mx_router(
    const float* __restrict__ h2, const float* __restrict__ gw,
    int* __restrict__ meta, int* __restrict__ tki, float* __restrict__ tkw)
{
  int t = blockIdx.x, tid = threadIdx.x;
  float p[8] = {0,0,0,0,0,0,0,0};
  const float* row = h2 + (size_t)t*H_;
  for (int i = tid; i < H_; i += 256) {
    float x = row[i];
    #pragma unroll
    for (int e=0;e<8;e++) p[e] += x * gw[e*H_ + i];
  }
  #pragma unroll
  for (int e=0;e<8;e++)
    #pragma unroll
    for (int d=32; d; d>>=1) p[e] += __shfl_down(p[e], d);
  __shared__ float red[4][8];
  int w = tid>>6;
  if ((tid&63)==0){
    #pragma unroll
    for (int e=0;e<8;e++) red[w][e] = p[e];
  }
  __syncthreads();
  if (tid==0){
    float lg[8];
    #pragma unroll
    for (int e=0;e<8;e++) lg[e] = red[0][e]+red[1][e]+red[2][e]+red[3][e];
    int e0 = 0;
    for (int e=1;e<8;e++) if (lg[e] > lg[e0]) e0 = e;
    int e1 = (e0==0)?1:0;
    for (int e=0;e<8;e++) if (e!=e0 && lg[e] > lg[e1]) e1 = e;
    float w0 = 1.f/(1.f + __expf(lg[e1]-lg[e0]));
    tki[t*2]=e0; tki[t*2+1]=e1; tkw[t*2]=w0; tkw[t*2+1]=1.f-w0;
    atomicAdd(&meta[e0],1); atomicAdd(&meta[e1],1);
  }
}

// meta: [0..7]=counts [8..15]=poff [16..23]=ptiles [24..31]=cursor; gsh = tile granularity shift
__global__ void mx_scan(int* __restrict__ meta, int* __restrict__ perm, int gsh)
{
  if (threadIdx.x == 0){
    int run = 0;
    for (int e=0;e<8;e++){
      meta[8+e] = run;
      int pt = (meta[e] + (1<<gsh) - 1) >> gsh;
      meta[16+e] = pt;
      run += pt << gsh;
      meta[24+e] = 0;
    }
  }
  for (int i = threadIdx.x; i < PROWS; i += 256) perm[i] = 0;
}

__global__ void mx_scatter(const int* __restrict__ tki, int* __restrict__ meta,
                           int* __restrict__ perm, int* __restrict__ slot)
{
  int t = blockIdx.x*256 + threadIdx.x;
  if (t >= T_) return;
  #pragma unroll
  for (int j=0;j<2;j++){
    int e = tki[t*2+j];
    int s = atomicAdd(&meta[24+e], 1);
    int pos = meta[8+e] + s;
    perm[pos] = t;
    slot[t*2+j] = pos;
  }
}

__global__ void mx_combine(const float* __restrict__ Y2, const int* __restrict__ slot,
                           const float* __restrict__ tkw, float* __restrict__ out)
{
  int t = blockIdx.x, tid = threadIdx.x;
  int s0 = slot[t*2], s1 = slot[t*2+1];
  float w0 = tkw[t*2], w1 = tkw[t*2+1];
  const float4* r0 = (const float4*)(Y2 + (size_t)s0*H_);
  const float4* r1 = (const float4*)(Y2 + (size_t)s1*H_);
  float4* o4 = (float4*)(out + (size_t)t*H_);
  for (int i = tid; i < 512; i += 256){
    float4 a = r0[i], b = r1[i], c;
    c.x = w0*a.x + w1*b.x; c.y = w0*a.y + w1*b.y;
    c.z = w0*a.z + w1*b.z; c.w = w0*a.w + w1*b.w;
    o4[i] = c;
  }
}

extern "C" void kernel_launch(void* const* d_in, const int* in_sizes, int n_in,
                              void* d_out, int out_size, void* d_ws, size_t ws_size,
                              hipStream_t stream)
{
  (void)in_sizes; (void)n_in; (void)out_size;
  const int*   positions = (const int*)  d_in[0];
  const float* hidden    = (const float*)d_in[1];
  const float* residual  = (const float*)d_in[2];
  const float* ln1       = (const float*)d_in[3];
  const float* ln2       = (const float*)d_in[4];
  const float* wq        = (const float*)d_in[5];
  const float* wk        = (const float*)d_in[6];
  const float* wv        = (const float*)d_in[7];
  const float* wo        = (const float*)d_in[8];
  const float* gatew     = (const float*)d_in[9];
  const float* w1        = (const float*)d_in[10];
  const float* w3        = (const float*)d_in[11];
  const float* w2        = (const float*)d_in[12];
  float* outp = (float*)d_out;                 // [T*H] moe out, then [T*H] residual
  char* ws = (char*)d_ws;

  size_t off = 0;
  auto alloc = [&](size_t n){ size_t o = off; off += (n + 255) & ~(size_t)255; return o; };
  float* cosT = (float*)(ws + alloc((size_t)T_*64*4));
  float* sinT = (float*)(ws + alloc((size_t)T_*64*4));
  size_t res1_off = alloc((size_t)T_*H_*4);
  float* res1 = (float*)(ws + res1_off);
  u16*   h1h  = (u16*)  (ws + alloc((size_t)T_*H_*2));
  u16*   h1l  = (u16*)  (ws + alloc((size_t)T_*H_*2));
  float* qkvF = (float*)(ws + alloc((size_t)T_*3072*4));
  size_t qh_off = alloc((size_t)NH*T_*HD*2);
  u16*   qh   = (u16*)  (ws + qh_off);
  u16*   ql   = (u16*)  (ws + alloc((size_t)NH*T_*HD*2));
  u16*   kh   = (u16*)  (ws + alloc((size_t)NKV*T_*HD*2));
  u16*   kl   = (u16*)  (ws + alloc((size_t)NKV*T_*HD*2));
  u16*   vh   = (u16*)  (ws + alloc((size_t)NKV*T_*HD*2));
  u16*   vl   = (u16*)  (ws + alloc((size_t)NKV*T_*HD*2));
  u16*   aoh  = (u16*)  (ws + alloc((size_t)T_*2048*2));
  u16*   aol  = (u16*)  (ws + alloc((size_t)T_*2048*2));
  float* oF   = (float*)(ws + alloc((size_t)T_*H_*4));
  float* h2f  = (float*)(ws + alloc((size_t)T_*H_*4));
  u16*   h2b  = (u16*)  (ws + alloc((size_t)T_*H_*2));
  int*   meta = (int*)  (ws + alloc(32*4));
  int*   tki  = (int*)  (ws + alloc((size_t)T_*2*4));
  float* tkw  = (float*)(ws + alloc((size_t)T_*2*4));
  int*   slot = (int*)  (ws + alloc((size_t)T_*2*4));
  int*   perm = (int*)  (ws + alloc((size_t)PROWS*4));
  u16*   Y1   = (u16*)  (ws + alloc((size_t)PROWS*II_*2));
  // Y2 aliases qh..oF (dead before the w2 GEMM)
  float* Y2   = (float*)(ws + qh_off);
  u16* w1b = (u16*)(ws + alloc((size_t)NE*II_*H_*2));
  u16* w3b = (u16*)(ws + alloc((size_t)NE*II_*H_*2));
  u16* w2b = (u16*)(ws + alloc((size_t)NE*H_*II_*2));
  u16* qwh = (u16*)(ws + alloc((size_t)3072*H_*2));   // wq|wk|wv rows concat, split-hi
  u16* qwl = (u16*)(ws + alloc((size_t)3072*H_*2));
  u16* woh = (u16*)(ws + alloc((size_t)H_*H_*2));
  u16* wol = (u16*)(ws + alloc((size_t)H_*H_*2));

  // 0. small split conversions (attention-path weights)
  mx_cvt_split<<<512, 256, 0, stream>>>(wq, qwh,             qwl,             2048*2048/8);
  mx_cvt_split<<<512, 256, 0, stream>>>(wk, qwh + 2048*2048, qwl + 2048*2048, 512*2048/8);
  mx_cvt_split<<<512, 256, 0, stream>>>(wv, qwh + 2560*2048, qwl + 2560*2048, 512*2048/8);
  mx_cvt_split<<<512, 256, 0, stream>>>(wo, woh,             wol,             2048*2048/8);
  // 1. RoPE tables + fused add+norm1
  mx_rope_table<<<512, 256, 0, stream>>>(positions, cosT, sinT);
  mx_addnorm<<<T_, 256, 0, stream>>>(hidden, residual, ln1, res1, h1h, h1l,
                                     nullptr, nullptr, nullptr);
  // 2. QKV projection (3-pass split, fused single launch)
  mx_gemm3g<16,24><<<384, 256, 0, stream>>>(h1h, h1l, qwh, qwl, qkvF, 3072, H_);
  // 3. RoPE apply + V transpose
  mx_rope_apply<<<dim3(T_/4, NH+NKV), 256, 0, stream>>>(qkvF, cosT, sinT, qh, ql, kh, kl);
  mx_transpose_v<<<dim3(NKV, T_/64), 256, 0, stream>>>(qkvF, vh, vl);
  // 4. attention (y<8) + MoE weight conversion helpers (y>=8, 3840 blocks)
  mx_attn<<<dim3(T_/64, 128), 512, 0, stream>>>(qh, ql, kh, kl, vh, vl, aoh, aol,
                                                w1, w3, w2, w1b, w3b, w2b);
  // 5. o_proj (3-pass split)
  mx_gemm3g<16,16><<<256, 256, 0, stream>>>(aoh, aol, woh, wol, oF, 2048, 2048);
  // 6. add + norm2 (residual output + h2 fp32 + h2 bf16); zero expert counts
  mx_addnorm<<<T_, 256, 0, stream>>>(oF, res1, ln2, outp + (size_t)T_*H_,
                                     nullptr, nullptr, h2f, h2b, meta);
  // 7. router + routing metadata
  mx_router<<<T_, 256, 0, stream>>>(h2f, gatew, meta, tki, tkw);
  mx_scan<<<1, 256, 0, stream>>>(meta, perm, 7);
  mx_scatter<<<T_/256, 256, 0, stream>>>(tki, meta, perm, slot);
  // 8. MoE expert GEMMs
  mx_moe_w13<32><<<4096, 256, 0, stream>>>(h2b, w1b, w3b, Y1, perm, meta);
  mx_moe_w2k<16><<<2048, 256, 0, stream>>>(Y1, w2b, Y2, meta);
  // 9. combine weighted expert outputs -> out
  mx_combine<<<T_, 256, 0, stream>>>(Y2, slot, tkw, outp);
  (void)ws_size;
}